// Round 1
// baseline (3795.552 us; speedup 1.0000x reference)
//
#include <hip/hip_runtime.h>

typedef unsigned short u16;
typedef unsigned int u32;
typedef __bf16 bf16x8 __attribute__((ext_vector_type(8)));
typedef float f32x4 __attribute__((ext_vector_type(4)));

#define DEVFN __device__ __forceinline__

constexpr int kB = 2, kS = 1024, kD = 2048, kH = 16, kKVH = 4, kHD = 128;
constexpr int kHID = 4096, kE = 8;
constexpr int kRows = kB * kS;               // 2048 tokens
constexpr int kQKVN = kH*kHD + 2*kKVH*kHD;   // 3072 fused qkv cols
constexpr float kEps = 1e-5f;
constexpr float kNeg = -1000000000.0f;

DEVFN u16 f2bf(float f) {
  u32 u = __float_as_uint(f);
  return (u16)((u + 0x7fffu + ((u >> 16) & 1u)) >> 16);
}

// ---------------- RMSNorm (f32 out) ----------------
__global__ __launch_bounds__(256) void rms_f32_kernel(const float* __restrict__ in,
    const float* __restrict__ w, float* __restrict__ out) {
  int row = blockIdx.x, tid = threadIdx.x;
  const float* x = in + (size_t)row * kD;
  float4 v0 = *(const float4*)&x[tid*8];
  float4 v1 = *(const float4*)&x[tid*8+4];
  float ss = v0.x*v0.x+v0.y*v0.y+v0.z*v0.z+v0.w*v0.w
           + v1.x*v1.x+v1.y*v1.y+v1.z*v1.z+v1.w*v1.w;
  #pragma unroll
  for (int off = 32; off; off >>= 1) ss += __shfl_xor(ss, off);
  __shared__ float red[4];
  if ((tid & 63) == 0) red[tid >> 6] = ss;
  __syncthreads();
  float tot = red[0] + red[1] + red[2] + red[3];
  float rs = rsqrtf(tot * (1.0f/kD) + kEps);
  float4 w0 = *(const float4*)&w[tid*8];
  float4 w1 = *(const float4*)&w[tid*8+4];
  float* o = out + (size_t)row * kD;
  float4 o0, o1;
  o0.x = v0.x*rs*w0.x; o0.y = v0.y*rs*w0.y; o0.z = v0.z*rs*w0.z; o0.w = v0.w*rs*w0.w;
  o1.x = v1.x*rs*w1.x; o1.y = v1.y*rs*w1.y; o1.z = v1.z*rs*w1.z; o1.w = v1.w*rs*w1.w;
  *(float4*)&o[tid*8] = o0;
  *(float4*)&o[tid*8+4] = o1;
}

// ---------------- RMSNorm (bf16 out) ----------------
__global__ __launch_bounds__(256) void rms_bf16_kernel(const float* __restrict__ in,
    const float* __restrict__ w, u16* __restrict__ out) {
  int row = blockIdx.x, tid = threadIdx.x;
  const float* x = in + (size_t)row * kD;
  float4 v0 = *(const float4*)&x[tid*8];
  float4 v1 = *(const float4*)&x[tid*8+4];
  float ss = v0.x*v0.x+v0.y*v0.y+v0.z*v0.z+v0.w*v0.w
           + v1.x*v1.x+v1.y*v1.y+v1.z*v1.z+v1.w*v1.w;
  #pragma unroll
  for (int off = 32; off; off >>= 1) ss += __shfl_xor(ss, off);
  __shared__ float red[4];
  if ((tid & 63) == 0) red[tid >> 6] = ss;
  __syncthreads();
  float tot = red[0] + red[1] + red[2] + red[3];
  float rs = rsqrtf(tot * (1.0f/kD) + kEps);
  float4 w0 = *(const float4*)&w[tid*8];
  float4 w1 = *(const float4*)&w[tid*8+4];
  union { int4 i4; u16 u[8]; } pk;
  pk.u[0] = f2bf(v0.x*rs*w0.x); pk.u[1] = f2bf(v0.y*rs*w0.y);
  pk.u[2] = f2bf(v0.z*rs*w0.z); pk.u[3] = f2bf(v0.w*rs*w0.w);
  pk.u[4] = f2bf(v1.x*rs*w1.x); pk.u[5] = f2bf(v1.y*rs*w1.y);
  pk.u[6] = f2bf(v1.z*rs*w1.z); pk.u[7] = f2bf(v1.w*rs*w1.w);
  *(int4*)&out[(size_t)row*kD + tid*8] = pk.i4;
}

// ---------------- f32 tiled GEMM: C[,coff+] = A@Bw (+X) ----------------
// A [M][lda], Bw [K][ldb] natural row-major, C [M][ldc]; 128x128 tile, BK=8,
// 256 thr, 8x8 per thread. All dims used are multiples of tile sizes.
template<bool ADDX>
__global__ __launch_bounds__(256) void gemm_f32_kernel(
    const float* __restrict__ A, int lda,
    const float* __restrict__ Bw, int ldb,
    float* __restrict__ C, int ldc, int coff,
    const float* __restrict__ X, int ldx,
    int K) {
  __shared__ float As[8][128];   // transposed A tile: As[k][m]
  __shared__ float Bs[8][128];
  int tid = threadIdx.x;
  int bm = blockIdx.y * 128, bn = blockIdx.x * 128;
  int ty = tid >> 4, tx = tid & 15;
  int ar = tid >> 1, ak = (tid & 1) * 4;
  int bkk = tid >> 5, bn4 = (tid & 31) * 4;
  float acc[8][8] = {};
  const float* Aptr = A + (size_t)(bm + ar) * lda + ak;
  const float* Bptr = Bw + (size_t)bkk * ldb + bn + bn4;
  for (int kt = 0; kt < K; kt += 8) {
    float4 av = *(const float4*)(Aptr + kt);
    float4 bv = *(const float4*)(Bptr + (size_t)kt * ldb);
    __syncthreads();
    As[ak+0][ar] = av.x; As[ak+1][ar] = av.y; As[ak+2][ar] = av.z; As[ak+3][ar] = av.w;
    *(float4*)&Bs[bkk][bn4] = bv;
    __syncthreads();
    #pragma unroll
    for (int k = 0; k < 8; ++k) {
      float a[8], b[8];
      *(float4*)&a[0] = *(const float4*)&As[k][ty*8];
      *(float4*)&a[4] = *(const float4*)&As[k][ty*8+4];
      *(float4*)&b[0] = *(const float4*)&Bs[k][tx*8];
      *(float4*)&b[4] = *(const float4*)&Bs[k][tx*8+4];
      #pragma unroll
      for (int i = 0; i < 8; ++i)
        #pragma unroll
        for (int j = 0; j < 8; ++j)
          acc[i][j] = fmaf(a[i], b[j], acc[i][j]);
    }
  }
  #pragma unroll
  for (int i = 0; i < 8; ++i) {
    size_t r = (size_t)(bm + ty*8 + i);
    float* crow = C + r * ldc + coff + bn + tx*8;
    #pragma unroll
    for (int j = 0; j < 8; j += 4) {
      float4 v;
      v.x = acc[i][j]; v.y = acc[i][j+1]; v.z = acc[i][j+2]; v.w = acc[i][j+3];
      if (ADDX) {
        float4 xv = *(const float4*)(X + r * ldx + bn + tx*8 + j);
        v.x += xv.x; v.y += xv.y; v.z += xv.z; v.w += xv.w;
      }
      *(float4*)(crow + j) = v;
    }
  }
}

// ---------------- RoPE in-place on fused qkv [rows][3072] ----------------
__global__ __launch_bounds__(256) void rope_kernel(float* __restrict__ qkv,
    const float* __restrict__ fc, const float* __restrict__ fs) {
  int idx = blockIdx.x * 256 + threadIdx.x;
  constexpr int NQ = kB*kS*kH*(kHD/2);       // 2097152
  constexpr int NK = kB*kS*kKVH*(kHD/2);     //  524288
  size_t base; int s, i;
  if (idx < NQ) {
    i = idx & 63; int h = (idx >> 6) & 15; s = (idx >> 10) & 1023; int b = idx >> 20;
    base = ((size_t)(b*kS + s))*kQKVN + h*kHD + 2*i;
  } else {
    int j = idx - NQ; if (j >= NK) return;
    i = j & 63; int h = (j >> 6) & 3; s = (j >> 8) & 1023; int b = j >> 18;
    base = ((size_t)(b*kS + s))*kQKVN + kH*kHD + h*kHD + 2*i;
  }
  float c = fc[s*64 + i], sn = fs[s*64 + i];
  float xr = qkv[base], xi = qkv[base+1];
  qkv[base]   = xr*c - xi*sn;
  qkv[base+1] = xr*sn + xi*c;
}

// ---------------- f32 flash attention (causal, GQA) ----------------
// block: 256 thr = one 32-row q-tile of one (b,h). K/V tiles of 32 staged in LDS.
__global__ __launch_bounds__(256) void attn_kernel(const float* __restrict__ qkv,
    float* __restrict__ out) {
  int qt = blockIdx.x, h = blockIdx.y, b = blockIdx.z;
  int kvh = h >> 2;
  int q0 = qt * 32;
  __shared__ float Qs[32][132], Ks[32][132], Vs[32][132], Ss[32][33];
  int tid = threadIdx.x;
  const float* qbase = qkv + ((size_t)(b*kS + q0)) * kQKVN + h * kHD;
  #pragma unroll
  for (int i = 0; i < 4; ++i) {
    int c = tid + 256*i; int r = c >> 5, cc = (c & 31) * 4;
    *(float4*)&Qs[r][cc] = *(const float4*)&qbase[(size_t)r * kQKVN + cc];
  }
  int tq = tid >> 3, t8 = tid & 7;
  float accO[16] = {};
  float m = -3.4e38f, l = 0.f;
  const float scale = 0.08838834764831845f;  // 128^-0.5
  int nkt = qt + 1;
  for (int kt = 0; kt < nkt; ++kt) {
    __syncthreads();   // WAR vs previous tile's reads
    const float* kbase = qkv + ((size_t)(b*kS + kt*32)) * kQKVN + kH*kHD + kvh * kHD;
    #pragma unroll
    for (int i = 0; i < 4; ++i) {
      int c = tid + 256*i; int r = c >> 5, cc = (c & 31) * 4;
      *(float4*)&Ks[r][cc] = *(const float4*)&kbase[(size_t)r * kQKVN + cc];
      *(float4*)&Vs[r][cc] = *(const float4*)&kbase[(size_t)r * kQKVN + kKVH*kHD + cc];
    }
    __syncthreads();
    // scores: thread -> row tq, keys {t8 + 8j}
    float sv[4] = {};
    for (int d0 = 0; d0 < kHD; d0 += 4) {
      float4 q4 = *(const float4*)&Qs[tq][d0];
      #pragma unroll
      for (int j = 0; j < 4; ++j) {
        float4 k4 = *(const float4*)&Ks[t8 + 8*j][d0];
        sv[j] += q4.x*k4.x + q4.y*k4.y + q4.z*k4.z + q4.w*k4.w;
      }
    }
    #pragma unroll
    for (int j = 0; j < 4; ++j) {
      int kabs = kt*32 + t8 + 8*j;
      sv[j] = sv[j] * scale + ((kabs > q0 + tq) ? kNeg : 0.f);
      Ss[tq][t8 + 8*j] = sv[j];
    }
    __syncthreads();
    float pm = -3.4e38f;
    #pragma unroll
    for (int k = 0; k < 32; ++k) pm = fmaxf(pm, Ss[tq][k]);
    float mn = fmaxf(m, pm);
    float cf = __expf(m - mn);
    m = mn; l *= cf;
    #pragma unroll
    for (int j = 0; j < 16; ++j) accO[j] *= cf;
    float pv[4];
    #pragma unroll
    for (int j = 0; j < 4; ++j) pv[j] = __expf(sv[j] - mn);
    __syncthreads();   // all raw-score reads done before overwrite with P
    #pragma unroll
    for (int j = 0; j < 4; ++j) Ss[tq][t8 + 8*j] = pv[j];
    __syncthreads();
    float rowsum = 0.f;
    for (int k = 0; k < 32; ++k) {
      float p = Ss[tq][k];
      rowsum += p;
      #pragma unroll
      for (int cch = 0; cch < 4; ++cch) {       // hd chunks t8*4 + 32*cch
        float4 v4 = *(const float4*)&Vs[k][4*t8 + 32*cch];
        accO[cch*4+0] = fmaf(p, v4.x, accO[cch*4+0]);
        accO[cch*4+1] = fmaf(p, v4.y, accO[cch*4+1]);
        accO[cch*4+2] = fmaf(p, v4.z, accO[cch*4+2]);
        accO[cch*4+3] = fmaf(p, v4.w, accO[cch*4+3]);
      }
    }
    l += rowsum;
  }
  float inv = 1.f / l;
  float* ob = out + ((size_t)(b*kS + q0 + tq)) * kD + h*kHD;
  #pragma unroll
  for (int cch = 0; cch < 4; ++cch) {
    float4 v;
    v.x = accO[cch*4+0]*inv; v.y = accO[cch*4+1]*inv;
    v.z = accO[cch*4+2]*inv; v.w = accO[cch*4+3]*inv;
    *(float4*)&ob[4*t8 + 32*cch] = v;
  }
}

// ---------------- gate: f32 logits, top-2, coef + token lists ----------------
__global__ void zero_counts_kernel(int* counts) {
  if (threadIdx.x < kE) counts[threadIdx.x] = 0;
}

__global__ __launch_bounds__(64) void gate_kernel(const float* __restrict__ h1,
    const float* __restrict__ wn, const float* __restrict__ gw,
    float* __restrict__ coef, int* __restrict__ lists, int* __restrict__ counts) {
  int row = blockIdx.x, lane = threadIdx.x;
  const float* x = h1 + (size_t)row * kD;
  float ss = 0.f;
  for (int d = lane; d < kD; d += 64) { float v = x[d]; ss = fmaf(v, v, ss); }
  #pragma unroll
  for (int off = 32; off; off >>= 1) ss += __shfl_xor(ss, off);
  float rs = rsqrtf(ss * (1.0f/kD) + kEps);
  float acc[kE] = {};
  for (int d = lane; d < kD; d += 64) {
    float g = x[d] * rs * wn[d];
    const float* gr = gw + (size_t)d * kE;
    #pragma unroll
    for (int e = 0; e < kE; ++e) acc[e] = fmaf(g, gr[e], acc[e]);
  }
  #pragma unroll
  for (int e = 0; e < kE; ++e)
    #pragma unroll
    for (int off = 32; off; off >>= 1) acc[e] += __shfl_xor(acc[e], off);
  if (lane == 0) {
    int i1 = 0; float l1 = acc[0];
    #pragma unroll
    for (int e = 1; e < kE; ++e) if (acc[e] > l1) { l1 = acc[e]; i1 = e; }
    int i2 = -1; float l2 = -3.4e38f;
    #pragma unroll
    for (int e = 0; e < kE; ++e) if (e != i1 && acc[e] > l2) { l2 = acc[e]; i2 = e; }
    float e2 = __expf(l2 - l1);
    float inv = 1.f / (1.f + e2);
    #pragma unroll
    for (int e = 0; e < kE; ++e) coef[row*kE + e] = 0.f;
    coef[row*kE + i1] = inv;
    coef[row*kE + i2] = e2 * inv;
    int p1 = atomicAdd(&counts[i1], 1); lists[i1*kRows + p1] = row;
    int p2 = atomicAdd(&counts[i2], 1); lists[i2*kRows + p2] = row;
  }
}

// ---------------- transpose+convert: f32 [R][C] -> bf16 [C][R] ----------------
__global__ void transpose_bf16_kernel(const float* __restrict__ in,
    u16* __restrict__ out, int R, int C) {
  __shared__ float tile[32][33];
  int c0 = blockIdx.x * 32, r0 = blockIdx.y * 32;
  int tx = threadIdx.x, ty = threadIdx.y;
  #pragma unroll
  for (int i = 0; i < 32; i += 8)
    tile[ty + i][tx] = in[(size_t)(r0 + ty + i) * C + c0 + tx];
  __syncthreads();
  #pragma unroll
  for (int i = 0; i < 32; i += 8)
    out[(size_t)(c0 + ty + i) * R + r0 + tx] = f2bf(tile[tx][ty + i]);
}

// ---------------- bf16 MFMA GEMM: C = A @ Bt^T ----------------
// A [*][lda] bf16 rows (AIDX: rows via ids), Bt [N][K] bf16, C f32.
// 128x128 tile, BK=64, 4 waves (2x2), 16x16x32 MFMA, XOR-swizzled LDS.
template<bool AIDX, bool SCATTER>
__global__ __launch_bounds__(256) void gemm_bf16_kernel(
    const u16* __restrict__ A, int lda,
    const u16* __restrict__ Bt,
    float* __restrict__ C, int ldc,
    const int* __restrict__ ids, const int* __restrict__ cntp,
    const float* __restrict__ coef, int expert, int K) {
  int cnt = (AIDX || SCATTER) ? *cntp : (int)(gridDim.y * 128);
  int bm = blockIdx.y * 128;
  if (bm >= cnt) return;
  int bn = blockIdx.x * 128;
  __shared__ __align__(16) char As[128*64*2];
  __shared__ __align__(16) char Bs[128*64*2];
  int tid = threadIdx.x;
  int lane = tid & 63, wid = tid >> 6;
  int wr = wid >> 1, wc = wid & 1;
  int hg = lane >> 4, lid = lane & 15;
  f32x4 acc[4][4] = {};
  const u16* arowp[4]; const u16* browp[4];
  #pragma unroll
  for (int i = 0; i < 4; ++i) {
    int c = tid + 256*i; int r = c >> 3;
    int ga;
    if (AIDX) { int rr = bm + r; if (rr >= cnt) rr = cnt - 1; ga = ids[rr]; }
    else ga = bm + r;
    arowp[i] = A + (size_t)ga * lda;
    browp[i] = Bt + (size_t)(bn + r) * K;
  }
  for (int kt = 0; kt < K; kt += 64) {
    __syncthreads();
    #pragma unroll
    for (int i = 0; i < 4; ++i) {
      int c = tid + 256*i; int r = c >> 3, s = c & 7;
      int4 va = *(const int4*)(arowp[i] + kt + s*8);
      int4 vb = *(const int4*)(browp[i] + kt + s*8);
      int off = (r*128 + s*16) ^ ((r & 7) << 4);
      *(int4*)(As + off) = va;
      *(int4*)(Bs + off) = vb;
    }
    __syncthreads();
    #pragma unroll
    for (int kk = 0; kk < 2; ++kk) {
      bf16x8 af[4], bfv[4];
      #pragma unroll
      for (int f = 0; f < 4; ++f) {
        int rA = wr*64 + f*16 + lid;
        af[f] = *(const bf16x8*)(As + ((rA*128 + kk*64 + hg*16) ^ ((rA & 7) << 4)));
        int rB = wc*64 + f*16 + lid;
        bfv[f] = *(const bf16x8*)(Bs + ((rB*128 + kk*64 + hg*16) ^ ((rB & 7) << 4)));
      }
      #pragma unroll
      for (int i = 0; i < 4; ++i)
        #pragma unroll
        for (int j = 0; j < 4; ++j)
          acc[i][j] = __builtin_amdgcn_mfma_f32_16x16x32_bf16(af[i], bfv[j], acc[i][j], 0, 0, 0);
    }
  }
  #pragma unroll
  for (int i = 0; i < 4; ++i) {
    #pragma unroll
    for (int rr = 0; rr < 4; ++rr) {
      int lr = wr*64 + i*16 + hg*4 + rr;
      int gr = bm + lr;
      if ((AIDX || SCATTER) && gr >= cnt) continue;
      #pragma unroll
      for (int j = 0; j < 4; ++j) {
        int gc = bn + wc*64 + j*16 + lid;
        float v = acc[i][j][rr];
        if (SCATTER) {
          int orow = ids[gr];
          float* p = C + (size_t)orow * ldc + gc;
          *p += v * coef[orow * kE + expert];
        } else {
          C[(size_t)gr * ldc + gc] = v;
        }
      }
    }
  }
}

// ---------------- silu(g1)*g3 -> bf16 hidden ----------------
__global__ __launch_bounds__(256) void silu_mul_kernel(const float* __restrict__ g1,
    const float* __restrict__ g3, u16* __restrict__ hid, const int* __restrict__ cntp) {
  int row = blockIdx.x;
  if (row >= *cntp) return;
  int tid = threadIdx.x;
  const float* a = g1 + (size_t)row * kHID;
  const float* b = g3 + (size_t)row * kHID;
  u16* o = hid + (size_t)row * kHID;
  #pragma unroll
  for (int it = 0; it < 4; ++it) {
    int c = it*1024 + tid*4;
    float4 av = *(const float4*)&a[c];
    float4 bv = *(const float4*)&b[c];
    ushort4 ov;
    ov.x = f2bf(av.x / (1.f + __expf(-av.x)) * bv.x);
    ov.y = f2bf(av.y / (1.f + __expf(-av.y)) * bv.y);
    ov.z = f2bf(av.z / (1.f + __expf(-av.z)) * bv.z);
    ov.w = f2bf(av.w / (1.f + __expf(-av.w)) * bv.w);
    *(ushort4*)&o[c] = ov;
  }
}

// ---------------- host launcher ----------------
extern "C" void kernel_launch(void* const* d_in, const int* in_sizes, int n_in,
                              void* d_out, int out_size, void* d_ws, size_t ws_size,
                              hipStream_t stream) {
  const float* x    = (const float*)d_in[0];
  const float* fcos = (const float*)d_in[1];
  const float* fsin = (const float*)d_in[2];
  const float* anw  = (const float*)d_in[5];
  const float* fnw  = (const float*)d_in[6];
  const float* wq   = (const float*)d_in[7];
  const float* wk   = (const float*)d_in[8];
  const float* wv   = (const float*)d_in[9];
  const float* wo   = (const float*)d_in[10];
  const float* gw   = (const float*)d_in[11];
  const float* w1   = (const float*)d_in[12];
  const float* w2   = (const float*)d_in[13];
  const float* w3   = (const float*)d_in[14];
  float* outp = (float*)d_out;

  char* ws = (char*)d_ws;
  size_t off = 0;
  auto alloc = [&](size_t bytes) -> void* {
    void* p = ws + off; off += (bytes + 255) & ~(size_t)255; return p;
  };
  float* h32   = (float*)alloc((size_t)kRows*kD*4);      // rmsnorm(x)
  float* qkv   = (float*)alloc((size_t)kRows*kQKVN*4);   // fused qkv (f32)
  float* attno = (float*)alloc((size_t)kRows*kD*4);      // attention out
  u16*   tbf   = (u16*)  alloc((size_t)kRows*kD*2);      // rmsnorm(h1) bf16
  float* coef  = (float*)alloc((size_t)kRows*kE*4);
  int*   counts= (int*)  alloc(kE*4);
  int*   lists = (int*)  alloc((size_t)kE*kRows*4);
  u16*   w1t   = (u16*)  alloc((size_t)kHID*kD*2);
  u16*   w3t   = (u16*)  alloc((size_t)kHID*kD*2);
  u16*   w2t   = (u16*)  alloc((size_t)kD*kHID*2);
  float* g1    = (float*)alloc((size_t)kRows*kHID*4);
  float* g3    = (float*)alloc((size_t)kRows*kHID*4);
  u16*   hid   = (u16*)  alloc((size_t)kRows*kHID*2);

  // ---- attention path: all f32 (gate-selection safety) ----
  rms_f32_kernel<<<kRows, 256, 0, stream>>>(x, anw, h32);
  gemm_f32_kernel<false><<<dim3(16,16), 256, 0, stream>>>(h32, kD, wq, 2048, qkv, kQKVN, 0,    nullptr, 0, kD);
  gemm_f32_kernel<false><<<dim3(4,16),  256, 0, stream>>>(h32, kD, wk, 512,  qkv, kQKVN, 2048, nullptr, 0, kD);
  gemm_f32_kernel<false><<<dim3(4,16),  256, 0, stream>>>(h32, kD, wv, 512,  qkv, kQKVN, 2560, nullptr, 0, kD);
  rope_kernel<<<(kB*kS*(kH+kKVH)*(kHD/2))/256, 256, 0, stream>>>(qkv, fcos, fsin);
  attn_kernel<<<dim3(kS/32, kH, kB), 256, 0, stream>>>(qkv, attno);
  gemm_f32_kernel<true><<<dim3(16,16), 256, 0, stream>>>(attno, kD, wo, kD, outp, kD, 0, x, kD, kD);

  // ---- gate (f32, from exact h1 in d_out) ----
  zero_counts_kernel<<<1, 64, 0, stream>>>(counts);
  gate_kernel<<<kRows, 64, 0, stream>>>(outp, fnw, gw, coef, lists, counts);
  rms_bf16_kernel<<<kRows, 256, 0, stream>>>(outp, fnw, tbf);

  // ---- MoE: bf16 MFMA per expert, d_out += coef * ff ----
  for (int e = 0; e < kE; ++e) {
    transpose_bf16_kernel<<<dim3(kHID/32, kD/32), dim3(32,8), 0, stream>>>(
        w1 + (size_t)e*kD*kHID, w1t, kD, kHID);
    transpose_bf16_kernel<<<dim3(kHID/32, kD/32), dim3(32,8), 0, stream>>>(
        w3 + (size_t)e*kD*kHID, w3t, kD, kHID);
    transpose_bf16_kernel<<<dim3(kD/32, kHID/32), dim3(32,8), 0, stream>>>(
        w2 + (size_t)e*kHID*kD, w2t, kHID, kD);
    gemm_bf16_kernel<true,false><<<dim3(kHID/128, kRows/128), 256, 0, stream>>>(
        tbf, kD, w1t, g1, kHID, lists + e*kRows, counts + e, nullptr, e, kD);
    gemm_bf16_kernel<true,false><<<dim3(kHID/128, kRows/128), 256, 0, stream>>>(
        tbf, kD, w3t, g3, kHID, lists + e*kRows, counts + e, nullptr, e, kD);
    silu_mul_kernel<<<kRows, 256, 0, stream>>>(g1, g3, hid, counts + e);
    gemm_bf16_kernel<false,true><<<dim3(kD/128, kRows/128), 256, 0, stream>>>(
        hid, kHID, w2t, outp, kD, lists + e*kRows, counts + e, coef, e, kHID);
  }
}

// Round 2
// 2142.336 us; speedup vs baseline: 1.7717x; 1.7717x over previous
//
#include <hip/hip_runtime.h>

typedef unsigned short u16;
typedef unsigned int u32;
typedef __bf16 bf16x8 __attribute__((ext_vector_type(8)));
typedef _Float16 f16;
typedef f16 f16x8 __attribute__((ext_vector_type(8)));
typedef float f32x4 __attribute__((ext_vector_type(4)));

#define DEVFN __device__ __forceinline__

constexpr int kB = 2, kS = 1024, kD = 2048, kH = 16, kKVH = 4, kHD = 128;
constexpr int kHID = 4096, kE = 8;
constexpr int kRows = kB * kS;               // 2048 tokens
constexpr int kQKVN = kH*kHD + 2*kKVH*kHD;   // 3072 fused qkv cols
constexpr float kEps = 1e-5f;
constexpr float kNeg = -1000000000.0f;
constexpr float kScale = 0.08838834764831845f; // 128^-0.5

DEVFN u16 f2bf(float f) {
  u32 u = __float_as_uint(f);
  return (u16)((u + 0x7fffu + ((u >> 16) & 1u)) >> 16);
}

DEVFN void split8v(float4 a, float4 b, f16x8& hi, f16x8& lo) {
  float v[8] = {a.x, a.y, a.z, a.w, b.x, b.y, b.z, b.w};
  #pragma unroll
  for (int e = 0; e < 8; ++e) {
    f16 h = (f16)v[e];
    hi[e] = h;
    lo[e] = (f16)(v[e] - (float)h);
  }
}

// ---------------- RMSNorm (f32 out) ----------------
__global__ __launch_bounds__(256) void rms_f32_kernel(const float* __restrict__ in,
    const float* __restrict__ w, float* __restrict__ out) {
  int row = blockIdx.x, tid = threadIdx.x;
  const float* x = in + (size_t)row * kD;
  float4 v0 = *(const float4*)&x[tid*8];
  float4 v1 = *(const float4*)&x[tid*8+4];
  float ss = v0.x*v0.x+v0.y*v0.y+v0.z*v0.z+v0.w*v0.w
           + v1.x*v1.x+v1.y*v1.y+v1.z*v1.z+v1.w*v1.w;
  #pragma unroll
  for (int off = 32; off; off >>= 1) ss += __shfl_xor(ss, off);
  __shared__ float red[4];
  if ((tid & 63) == 0) red[tid >> 6] = ss;
  __syncthreads();
  float tot = red[0] + red[1] + red[2] + red[3];
  float rs = rsqrtf(tot * (1.0f/kD) + kEps);
  float4 w0 = *(const float4*)&w[tid*8];
  float4 w1 = *(const float4*)&w[tid*8+4];
  float* o = out + (size_t)row * kD;
  float4 o0, o1;
  o0.x = v0.x*rs*w0.x; o0.y = v0.y*rs*w0.y; o0.z = v0.z*rs*w0.z; o0.w = v0.w*rs*w0.w;
  o1.x = v1.x*rs*w1.x; o1.y = v1.y*rs*w1.y; o1.z = v1.z*rs*w1.z; o1.w = v1.w*rs*w1.w;
  *(float4*)&o[tid*8] = o0;
  *(float4*)&o[tid*8+4] = o1;
}

// ---------------- RMSNorm (bf16 out) ----------------
__global__ __launch_bounds__(256) void rms_bf16_kernel(const float* __restrict__ in,
    const float* __restrict__ w, u16* __restrict__ out) {
  int row = blockIdx.x, tid = threadIdx.x;
  const float* x = in + (size_t)row * kD;
  float4 v0 = *(const float4*)&x[tid*8];
  float4 v1 = *(const float4*)&x[tid*8+4];
  float ss = v0.x*v0.x+v0.y*v0.y+v0.z*v0.z+v0.w*v0.w
           + v1.x*v1.x+v1.y*v1.y+v1.z*v1.z+v1.w*v1.w;
  #pragma unroll
  for (int off = 32; off; off >>= 1) ss += __shfl_xor(ss, off);
  __shared__ float red[4];
  if ((tid & 63) == 0) red[tid >> 6] = ss;
  __syncthreads();
  float tot = red[0] + red[1] + red[2] + red[3];
  float rs = rsqrtf(tot * (1.0f/kD) + kEps);
  float4 w0 = *(const float4*)&w[tid*8];
  float4 w1 = *(const float4*)&w[tid*8+4];
  union { int4 i4; u16 u[8]; } pk;
  pk.u[0] = f2bf(v0.x*rs*w0.x); pk.u[1] = f2bf(v0.y*rs*w0.y);
  pk.u[2] = f2bf(v0.z*rs*w0.z); pk.u[3] = f2bf(v0.w*rs*w0.w);
  pk.u[4] = f2bf(v1.x*rs*w1.x); pk.u[5] = f2bf(v1.y*rs*w1.y);
  pk.u[6] = f2bf(v1.z*rs*w1.z); pk.u[7] = f2bf(v1.w*rs*w1.w);
  *(int4*)&out[(size_t)row*kD + tid*8] = pk.i4;
}

// ------- transpose + f16-split: in f32 [R][C] -> hi/lo [C-offset rows][R] -------
__global__ void transpose_split_kernel(const float* __restrict__ in,
    f16* __restrict__ hi, f16* __restrict__ lo, int R, int C, int noff, int ldout) {
  __shared__ float tile[32][33];
  int c0 = blockIdx.x * 32, r0 = blockIdx.y * 32;
  int tx = threadIdx.x, ty = threadIdx.y;
  #pragma unroll
  for (int i = 0; i < 32; i += 8)
    tile[ty + i][tx] = in[(size_t)(r0 + ty + i) * C + c0 + tx];
  __syncthreads();
  #pragma unroll
  for (int i = 0; i < 32; i += 8) {
    float v = tile[tx][ty + i];
    f16 h = (f16)v;
    size_t o = (size_t)(noff + c0 + ty + i) * ldout + r0 + tx;
    hi[o] = h;
    lo[o] = (f16)(v - (float)h);
  }
}

// ------- transpose f32: qkv V-columns -> vT [b][kvh*128+d][S] -------
__global__ void vt_transpose_kernel(const float* __restrict__ qkv, float* __restrict__ vT) {
  __shared__ float tile[32][33];
  int s0 = blockIdx.x * 32, c0 = blockIdx.y * 32, b = blockIdx.z;
  int tx = threadIdx.x, ty = threadIdx.y;
  #pragma unroll
  for (int i = 0; i < 32; i += 8)
    tile[ty + i][tx] = qkv[(size_t)(b*kS + s0 + ty + i) * kQKVN + kH*kHD + kKVH*kHD + c0 + tx];
  __syncthreads();
  #pragma unroll
  for (int i = 0; i < 32; i += 8)
    vT[(size_t)(b*kKVH*kHD + c0 + ty + i) * kS + s0 + tx] = tile[tx][ty + i];
}

// ---------------- split-f16 GEMM: C = A(f32) @ B^T, f32-equivalent precision ----
// A [M][lda] f32, Bhi/Blo [N][K] f16 rows, C [M][ldc] f32 at col offset coff.
// 128x128 tile, BK=64, 4 waves 2x2, mfma 16x16x32_f16 x3 (hh, hl, lh).
template<bool ADDX>
__global__ __launch_bounds__(256) void gemm_sf16_kernel(
    const float* __restrict__ A, int lda,
    const f16* __restrict__ Bhi, const f16* __restrict__ Blo,
    float* __restrict__ C, int ldc, int coff,
    const float* __restrict__ X, int ldx, int K) {
  __shared__ __align__(16) char Ah[128*64*2], Al[128*64*2];
  __shared__ __align__(16) char Bh[128*64*2], Bl[128*64*2];
  int tid = threadIdx.x;
  int bm = blockIdx.y * 128, bn = blockIdx.x * 128;
  int lane = tid & 63, wid = tid >> 6;
  int wr = wid >> 1, wc = wid & 1;
  int hg = lane >> 4, lid = lane & 15;
  f32x4 acc[4][4] = {};
  int ar = tid >> 1, ak = (tid & 1) * 32;
  const float* Ap = A + (size_t)(bm + ar) * lda + ak;

  for (int kt = 0; kt < K; kt += 64) {
    float4 a4[8];
    #pragma unroll
    for (int s = 0; s < 8; ++s) a4[s] = *(const float4*)(Ap + kt + s*4);
    int4 bvh[4], bvl[4];
    #pragma unroll
    for (int it = 0; it < 4; ++it) {
      int c = it*256 + tid; int r = c >> 3, t = c & 7;
      const f16* bp = Bhi + (size_t)(bn + r) * K + kt + t*8;
      const f16* bq = Blo + (size_t)(bn + r) * K + kt + t*8;
      bvh[it] = *(const int4*)bp;
      bvl[it] = *(const int4*)bq;
    }
    __syncthreads();
    #pragma unroll
    for (int s8 = 0; s8 < 4; ++s8) {
      f16x8 hi, lo;
      split8v(a4[s8*2], a4[s8*2+1], hi, lo);
      int off = (ar*128 + ak*2 + s8*16) ^ ((ar & 7) << 4);
      *(f16x8*)(Ah + off) = hi;
      *(f16x8*)(Al + off) = lo;
    }
    #pragma unroll
    for (int it = 0; it < 4; ++it) {
      int c = it*256 + tid; int r = c >> 3, t = c & 7;
      int off = (r*128 + t*16) ^ ((r & 7) << 4);
      *(int4*)(Bh + off) = bvh[it];
      *(int4*)(Bl + off) = bvl[it];
    }
    __syncthreads();
    #pragma unroll
    for (int kk = 0; kk < 2; ++kk) {
      f16x8 ah[4], al[4], bh[4], bl[4];
      #pragma unroll
      for (int f = 0; f < 4; ++f) {
        int rA = wr*64 + f*16 + lid;
        int oA = (rA*128 + kk*64 + hg*16) ^ ((rA & 7) << 4);
        ah[f] = *(const f16x8*)(Ah + oA);
        al[f] = *(const f16x8*)(Al + oA);
        int rB = wc*64 + f*16 + lid;
        int oB = (rB*128 + kk*64 + hg*16) ^ ((rB & 7) << 4);
        bh[f] = *(const f16x8*)(Bh + oB);
        bl[f] = *(const f16x8*)(Bl + oB);
      }
      #pragma unroll
      for (int i = 0; i < 4; ++i)
        #pragma unroll
        for (int j = 0; j < 4; ++j) {
          acc[i][j] = __builtin_amdgcn_mfma_f32_16x16x32_f16(ah[i], bh[j], acc[i][j], 0, 0, 0);
          acc[i][j] = __builtin_amdgcn_mfma_f32_16x16x32_f16(ah[i], bl[j], acc[i][j], 0, 0, 0);
          acc[i][j] = __builtin_amdgcn_mfma_f32_16x16x32_f16(al[i], bh[j], acc[i][j], 0, 0, 0);
        }
    }
  }
  #pragma unroll
  for (int i = 0; i < 4; ++i) {
    #pragma unroll
    for (int rr = 0; rr < 4; ++rr) {
      size_t gr = (size_t)(bm + wr*64 + i*16 + hg*4 + rr);
      #pragma unroll
      for (int j = 0; j < 4; ++j) {
        int gc = bn + wc*64 + j*16 + lid;
        float v = acc[i][j][rr];
        if (ADDX) v += X[gr * ldx + gc];
        C[gr * ldc + coff + gc] = v;
      }
    }
  }
}

// ---------------- RoPE in-place on fused qkv [rows][3072] ----------------
__global__ __launch_bounds__(256) void rope_kernel(float* __restrict__ qkv,
    const float* __restrict__ fc, const float* __restrict__ fs) {
  int idx = blockIdx.x * 256 + threadIdx.x;
  constexpr int NQ = kB*kS*kH*(kHD/2);
  constexpr int NK = kB*kS*kKVH*(kHD/2);
  size_t base; int s, i;
  if (idx < NQ) {
    i = idx & 63; int h = (idx >> 6) & 15; s = (idx >> 10) & 1023; int b = idx >> 20;
    base = ((size_t)(b*kS + s))*kQKVN + h*kHD + 2*i;
  } else {
    int j = idx - NQ; if (j >= NK) return;
    i = j & 63; int h = (j >> 6) & 3; s = (j >> 8) & 1023; int b = j >> 18;
    base = ((size_t)(b*kS + s))*kQKVN + kH*kHD + h*kHD + 2*i;
  }
  float c = fc[s*64 + i], sn = fs[s*64 + i];
  float xr = qkv[base], xi = qkv[base+1];
  qkv[base]   = xr*c - xi*sn;
  qkv[base+1] = xr*sn + xi*c;
}

// ---------------- split-f16 MFMA flash attention (causal, GQA) ----------------
// block = 64 q-rows of one (b,h); 4 waves, each 16 q-rows. KV tile 64.
__global__ __launch_bounds__(256) void attn_sf16_kernel(const float* __restrict__ qkv,
    const float* __restrict__ vT, float* __restrict__ out) {
  int qt = (int)gridDim.x - 1 - blockIdx.x;   // big tiles first
  int h = blockIdx.y, b = blockIdx.z;
  int kvh = h >> 2;
  int q0 = qt * 64;
  __shared__ __align__(16) char Kh[64*128*2], Kl[64*128*2];
  __shared__ __align__(16) char Vh[128*64*2], Vl[128*64*2];
  __shared__ __align__(16) char Ph[4][16*64*2], Pl[4][16*64*2];
  int tid = threadIdx.x, lane = tid & 63, w = tid >> 6;
  int hg = lane >> 4, lid = lane & 15;

  // Q fragments in registers (split f16)
  f16x8 qh[4], ql[4];
  {
    const float* qrow = qkv + (size_t)(b*kS + q0 + w*16 + lid) * kQKVN + h*kHD;
    #pragma unroll
    for (int ks = 0; ks < 4; ++ks) {
      float4 a = *(const float4*)(qrow + ks*32 + hg*8);
      float4 c = *(const float4*)(qrow + ks*32 + hg*8 + 4);
      split8v(a, c, qh[ks], ql[ks]);
    }
  }
  f32x4 oacc[8] = {};
  float m[4] = {-3.0e38f, -3.0e38f, -3.0e38f, -3.0e38f};
  float lsum[4] = {};
  char* Phw = Ph[w];
  char* Plw = Pl[w];

  for (int kt = 0; kt <= qt; ++kt) {
    __syncthreads();
    // stage K tile [64 kv][128 d] (split, swizzled)
    {
      int r = tid >> 2, c0 = (tid & 3) * 32;
      const float* kr = qkv + (size_t)(b*kS + kt*64 + r) * kQKVN + kH*kHD + kvh*kHD + c0;
      #pragma unroll
      for (int s8 = 0; s8 < 4; ++s8) {
        float4 a = *(const float4*)(kr + s8*8);
        float4 c = *(const float4*)(kr + s8*8 + 4);
        f16x8 hi, lo; split8v(a, c, hi, lo);
        int off = (r*256 + c0*2 + s8*16) ^ ((r & 7) << 4);
        *(f16x8*)(Kh + off) = hi;
        *(f16x8*)(Kl + off) = lo;
      }
    }
    // stage V^T tile [128 d][64 kv]
    {
      int r = tid >> 1, c0 = (tid & 1) * 32;
      const float* vr = vT + (size_t)(b*kKVH*kHD + kvh*kHD + r) * kS + kt*64 + c0;
      #pragma unroll
      for (int s8 = 0; s8 < 4; ++s8) {
        float4 a = *(const float4*)(vr + s8*8);
        float4 c = *(const float4*)(vr + s8*8 + 4);
        f16x8 hi, lo; split8v(a, c, hi, lo);
        int off = (r*128 + c0*2 + s8*16) ^ ((r & 7) << 4);
        *(f16x8*)(Vh + off) = hi;
        *(f16x8*)(Vl + off) = lo;
      }
    }
    __syncthreads();

    // QK^T: S[16 q][64 kv] per wave
    f32x4 sacc[4] = {};
    #pragma unroll
    for (int ks = 0; ks < 4; ++ks) {
      #pragma unroll
      for (int j = 0; j < 4; ++j) {
        int rB = j*16 + lid;
        int off = (rB*256 + ks*64 + hg*16) ^ ((rB & 7) << 4);
        f16x8 kh = *(const f16x8*)(Kh + off);
        f16x8 klo = *(const f16x8*)(Kl + off);
        sacc[j] = __builtin_amdgcn_mfma_f32_16x16x32_f16(qh[ks], kh, sacc[j], 0, 0, 0);
        sacc[j] = __builtin_amdgcn_mfma_f32_16x16x32_f16(qh[ks], klo, sacc[j], 0, 0, 0);
        sacc[j] = __builtin_amdgcn_mfma_f32_16x16x32_f16(ql[ks], kh, sacc[j], 0, 0, 0);
      }
    }
    // softmax (online)
    float s[4][4], ps[4][4];
    bool diag = (kt == qt);
    #pragma unroll
    for (int j = 0; j < 4; ++j)
      #pragma unroll
      for (int r = 0; r < 4; ++r) {
        float v = sacc[j][r] * kScale;
        if (diag) {
          int kvabs = kt*64 + j*16 + lid;
          int qabs = q0 + w*16 + hg*4 + r;
          if (kvabs > qabs) v = kNeg;
        }
        s[j][r] = v;
      }
    float pm[4], cf[4];
    #pragma unroll
    for (int r = 0; r < 4; ++r) {
      pm[r] = fmaxf(fmaxf(s[0][r], s[1][r]), fmaxf(s[2][r], s[3][r]));
      #pragma unroll
      for (int msk = 1; msk < 16; msk <<= 1) pm[r] = fmaxf(pm[r], __shfl_xor(pm[r], msk));
      float mn = fmaxf(m[r], pm[r]);
      cf[r] = __expf(m[r] - mn);
      m[r] = mn;
    }
    #pragma unroll
    for (int j2 = 0; j2 < 8; ++j2)
      #pragma unroll
      for (int r = 0; r < 4; ++r) oacc[j2][r] *= cf[r];
    float rs[4] = {};
    #pragma unroll
    for (int j = 0; j < 4; ++j)
      #pragma unroll
      for (int r = 0; r < 4; ++r) {
        float p = __expf(s[j][r] - m[r]);
        ps[j][r] = p;
        rs[r] += p;
      }
    #pragma unroll
    for (int r = 0; r < 4; ++r) lsum[r] = lsum[r]*cf[r] + rs[r];
    // write P (split) to per-wave LDS, layout [16 q][64 kv] swizzled
    #pragma unroll
    for (int j = 0; j < 4; ++j)
      #pragma unroll
      for (int r = 0; r < 4; ++r) {
        int q = hg*4 + r;
        int off = (q*128 + (j*16 + lid)*2) ^ ((q & 7) << 4);
        f16 ph = (f16)ps[j][r];
        *(f16*)(Phw + off) = ph;
        *(f16*)(Plw + off) = (f16)(ps[j][r] - (float)ph);
      }
    // PV: O[16 q][128 d] += P @ V
    #pragma unroll
    for (int kk2 = 0; kk2 < 2; ++kk2) {
      int oP = (lid*128 + kk2*64 + hg*16) ^ ((lid & 7) << 4);
      f16x8 pa_h = *(const f16x8*)(Phw + oP);
      f16x8 pa_l = *(const f16x8*)(Plw + oP);
      #pragma unroll
      for (int j2 = 0; j2 < 8; ++j2) {
        int rV = j2*16 + lid;
        int off = (rV*128 + kk2*64 + hg*16) ^ ((rV & 7) << 4);
        f16x8 vh = *(const f16x8*)(Vh + off);
        f16x8 vl = *(const f16x8*)(Vl + off);
        oacc[j2] = __builtin_amdgcn_mfma_f32_16x16x32_f16(pa_h, vh, oacc[j2], 0, 0, 0);
        oacc[j2] = __builtin_amdgcn_mfma_f32_16x16x32_f16(pa_h, vl, oacc[j2], 0, 0, 0);
        oacc[j2] = __builtin_amdgcn_mfma_f32_16x16x32_f16(pa_l, vh, oacc[j2], 0, 0, 0);
      }
    }
  }
  // finalize
  #pragma unroll
  for (int r = 0; r < 4; ++r) {
    #pragma unroll
    for (int msk = 1; msk < 16; msk <<= 1) lsum[r] += __shfl_xor(lsum[r], msk);
    lsum[r] = 1.f / lsum[r];
  }
  #pragma unroll
  for (int j2 = 0; j2 < 8; ++j2)
    #pragma unroll
    for (int r = 0; r < 4; ++r) {
      size_t o = (size_t)(b*kS + q0 + w*16 + hg*4 + r) * kD + h*kHD + j2*16 + lid;
      out[o] = oacc[j2][r] * lsum[r];
    }
}

// ---------------- gate: f32 logits, top-2, coef + token lists ----------------
__global__ void zero_counts_kernel(int* counts) {
  if (threadIdx.x < kE) counts[threadIdx.x] = 0;
}

__global__ __launch_bounds__(64) void gate_kernel(const float* __restrict__ h1,
    const float* __restrict__ wn, const float* __restrict__ gw,
    float* __restrict__ coef, int* __restrict__ lists, int* __restrict__ counts) {
  int row = blockIdx.x, lane = threadIdx.x;
  const float* x = h1 + (size_t)row * kD;
  float ss = 0.f;
  for (int d = lane; d < kD; d += 64) { float v = x[d]; ss = fmaf(v, v, ss); }
  #pragma unroll
  for (int off = 32; off; off >>= 1) ss += __shfl_xor(ss, off);
  float rs = rsqrtf(ss * (1.0f/kD) + kEps);
  float acc[kE] = {};
  for (int d = lane; d < kD; d += 64) {
    float g = x[d] * rs * wn[d];
    const float* gr = gw + (size_t)d * kE;
    #pragma unroll
    for (int e = 0; e < kE; ++e) acc[e] = fmaf(g, gr[e], acc[e]);
  }
  #pragma unroll
  for (int e = 0; e < kE; ++e)
    #pragma unroll
    for (int off = 32; off; off >>= 1) acc[e] += __shfl_xor(acc[e], off);
  if (lane == 0) {
    int i1 = 0; float l1 = acc[0];
    #pragma unroll
    for (int e = 1; e < kE; ++e) if (acc[e] > l1) { l1 = acc[e]; i1 = e; }
    int i2 = -1; float l2 = -3.4e38f;
    #pragma unroll
    for (int e = 0; e < kE; ++e) if (e != i1 && acc[e] > l2) { l2 = acc[e]; i2 = e; }
    float e2 = __expf(l2 - l1);
    float inv = 1.f / (1.f + e2);
    #pragma unroll
    for (int e = 0; e < kE; ++e) coef[row*kE + e] = 0.f;
    coef[row*kE + i1] = inv;
    coef[row*kE + i2] = e2 * inv;
    int p1 = atomicAdd(&counts[i1], 1); lists[i1*kRows + p1] = row;
    int p2 = atomicAdd(&counts[i2], 1); lists[i2*kRows + p2] = row;
  }
}

// ---------------- transpose+convert: f32 [R][C] -> bf16 [C][R] ----------------
__global__ void transpose_bf16_kernel(const float* __restrict__ in,
    u16* __restrict__ out, int R, int C) {
  __shared__ float tile[32][33];
  int c0 = blockIdx.x * 32, r0 = blockIdx.y * 32;
  int tx = threadIdx.x, ty = threadIdx.y;
  #pragma unroll
  for (int i = 0; i < 32; i += 8)
    tile[ty + i][tx] = in[(size_t)(r0 + ty + i) * C + c0 + tx];
  __syncthreads();
  #pragma unroll
  for (int i = 0; i < 32; i += 8)
    out[(size_t)(c0 + ty + i) * R + r0 + tx] = f2bf(tile[tx][ty + i]);
}

// ------- fused MoE up-proj: hid = bf16(silu(A@w1t^T) * (A@w3t^T)), gathered rows ------
__global__ __launch_bounds__(256) void gemm_w1w3_kernel(
    const u16* __restrict__ A, const u16* __restrict__ B1t, const u16* __restrict__ B3t,
    u16* __restrict__ hid, const int* __restrict__ ids, const int* __restrict__ cntp, int K) {
  int cnt = *cntp;
  int bm = blockIdx.y * 128;
  if (bm >= cnt) return;
  int bn = blockIdx.x * 128;
  __shared__ __align__(16) char As[128*64*2];
  __shared__ __align__(16) char B1s[128*64*2];
  __shared__ __align__(16) char B3s[128*64*2];
  int tid = threadIdx.x;
  int lane = tid & 63, wid = tid >> 6;
  int wr = wid >> 1, wc = wid & 1;
  int hg = lane >> 4, lid = lane & 15;
  f32x4 acc1[4][4] = {}, acc3[4][4] = {};
  const u16* arowp[4]; const u16* b1p[4]; const u16* b3p[4];
  #pragma unroll
  for (int i = 0; i < 4; ++i) {
    int c = tid + 256*i; int r = c >> 3;
    int rr = bm + r; if (rr >= cnt) rr = cnt - 1;
    arowp[i] = A + (size_t)ids[rr] * kD;
    b1p[i] = B1t + (size_t)(bn + r) * K;
    b3p[i] = B3t + (size_t)(bn + r) * K;
  }
  for (int kt = 0; kt < K; kt += 64) {
    __syncthreads();
    #pragma unroll
    for (int i = 0; i < 4; ++i) {
      int c = tid + 256*i; int r = c >> 3, sft = c & 7;
      int4 va = *(const int4*)(arowp[i] + kt + sft*8);
      int4 v1 = *(const int4*)(b1p[i] + kt + sft*8);
      int4 v3 = *(const int4*)(b3p[i] + kt + sft*8);
      int off = (r*128 + sft*16) ^ ((r & 7) << 4);
      *(int4*)(As + off) = va;
      *(int4*)(B1s + off) = v1;
      *(int4*)(B3s + off) = v3;
    }
    __syncthreads();
    #pragma unroll
    for (int kk = 0; kk < 2; ++kk) {
      bf16x8 af[4], b1f[4], b3f[4];
      #pragma unroll
      for (int f = 0; f < 4; ++f) {
        int rA = wr*64 + f*16 + lid;
        af[f] = *(const bf16x8*)(As + ((rA*128 + kk*64 + hg*16) ^ ((rA & 7) << 4)));
        int rB = wc*64 + f*16 + lid;
        int oB = (rB*128 + kk*64 + hg*16) ^ ((rB & 7) << 4);
        b1f[f] = *(const bf16x8*)(B1s + oB);
        b3f[f] = *(const bf16x8*)(B3s + oB);
      }
      #pragma unroll
      for (int i = 0; i < 4; ++i)
        #pragma unroll
        for (int j = 0; j < 4; ++j) {
          acc1[i][j] = __builtin_amdgcn_mfma_f32_16x16x32_bf16(af[i], b1f[j], acc1[i][j], 0, 0, 0);
          acc3[i][j] = __builtin_amdgcn_mfma_f32_16x16x32_bf16(af[i], b3f[j], acc3[i][j], 0, 0, 0);
        }
    }
  }
  #pragma unroll
  for (int i = 0; i < 4; ++i) {
    #pragma unroll
    for (int rr = 0; rr < 4; ++rr) {
      int gr = bm + wr*64 + i*16 + hg*4 + rr;
      if (gr >= cnt) continue;
      #pragma unroll
      for (int j = 0; j < 4; ++j) {
        int gc = bn + wc*64 + j*16 + lid;
        float a1 = acc1[i][j][rr], a3 = acc3[i][j][rr];
        float hv = a1 / (1.f + __expf(-a1)) * a3;
        hid[(size_t)gr * kHID + gc] = f2bf(hv);
      }
    }
  }
}

// ---------------- bf16 MFMA GEMM with scatter-add epilogue (w2) ----------------
__global__ __launch_bounds__(256) void gemm_w2_kernel(
    const u16* __restrict__ A, int lda,
    const u16* __restrict__ Bt,
    float* __restrict__ C, int ldc,
    const int* __restrict__ ids, const int* __restrict__ cntp,
    const float* __restrict__ coef, int expert, int K) {
  int cnt = *cntp;
  int bm = blockIdx.y * 128;
  if (bm >= cnt) return;
  int bn = blockIdx.x * 128;
  __shared__ __align__(16) char As[128*64*2];
  __shared__ __align__(16) char Bs[128*64*2];
  int tid = threadIdx.x;
  int lane = tid & 63, wid = tid >> 6;
  int wr = wid >> 1, wc = wid & 1;
  int hg = lane >> 4, lid = lane & 15;
  f32x4 acc[4][4] = {};
  const u16* arowp[4]; const u16* browp[4];
  #pragma unroll
  for (int i = 0; i < 4; ++i) {
    int c = tid + 256*i; int r = c >> 3;
    arowp[i] = A + (size_t)(bm + r) * lda;
    browp[i] = Bt + (size_t)(bn + r) * K;
  }
  for (int kt = 0; kt < K; kt += 64) {
    __syncthreads();
    #pragma unroll
    for (int i = 0; i < 4; ++i) {
      int c = tid + 256*i; int r = c >> 3, sft = c & 7;
      int4 va = *(const int4*)(arowp[i] + kt + sft*8);
      int4 vb = *(const int4*)(browp[i] + kt + sft*8);
      int off = (r*128 + sft*16) ^ ((r & 7) << 4);
      *(int4*)(As + off) = va;
      *(int4*)(Bs + off) = vb;
    }
    __syncthreads();
    #pragma unroll
    for (int kk = 0; kk < 2; ++kk) {
      bf16x8 af[4], bfv[4];
      #pragma unroll
      for (int f = 0; f < 4; ++f) {
        int rA = wr*64 + f*16 + lid;
        af[f] = *(const bf16x8*)(As + ((rA*128 + kk*64 + hg*16) ^ ((rA & 7) << 4)));
        int rB = wc*64 + f*16 + lid;
        bfv[f] = *(const bf16x8*)(Bs + ((rB*128 + kk*64 + hg*16) ^ ((rB & 7) << 4)));
      }
      #pragma unroll
      for (int i = 0; i < 4; ++i)
        #pragma unroll
        for (int j = 0; j < 4; ++j)
          acc[i][j] = __builtin_amdgcn_mfma_f32_16x16x32_bf16(af[i], bfv[j], acc[i][j], 0, 0, 0);
    }
  }
  #pragma unroll
  for (int i = 0; i < 4; ++i) {
    #pragma unroll
    for (int rr = 0; rr < 4; ++rr) {
      int gr = bm + wr*64 + i*16 + hg*4 + rr;
      if (gr >= cnt) continue;
      int orow = ids[gr];
      float cf = coef[orow * kE + expert];
      #pragma unroll
      for (int j = 0; j < 4; ++j) {
        int gc = bn + wc*64 + j*16 + lid;
        float* p = C + (size_t)orow * ldc + gc;
        *p += acc[i][j][rr] * cf;
      }
    }
  }
}

// ---------------- host launcher ----------------
extern "C" void kernel_launch(void* const* d_in, const int* in_sizes, int n_in,
                              void* d_out, int out_size, void* d_ws, size_t ws_size,
                              hipStream_t stream) {
  const float* x    = (const float*)d_in[0];
  const float* fcos = (const float*)d_in[1];
  const float* fsin = (const float*)d_in[2];
  const float* anw  = (const float*)d_in[5];
  const float* fnw  = (const float*)d_in[6];
  const float* wq   = (const float*)d_in[7];
  const float* wk   = (const float*)d_in[8];
  const float* wv   = (const float*)d_in[9];
  const float* wo   = (const float*)d_in[10];
  const float* gw   = (const float*)d_in[11];
  const float* w1   = (const float*)d_in[12];
  const float* w2   = (const float*)d_in[13];
  const float* w3   = (const float*)d_in[14];
  float* outp = (float*)d_out;

  char* ws = (char*)d_ws;
  size_t off = 0;
  auto alloc = [&](size_t bytes) -> void* {
    void* p = ws + off; off += (bytes + 255) & ~(size_t)255; return p;
  };
  float* h32   = (float*)alloc((size_t)kRows*kD*4);
  float* qkv   = (float*)alloc((size_t)kRows*kQKVN*4);
  float* vTb   = (float*)alloc((size_t)kB*kKVH*kHD*kS*4);
  float* attno = (float*)alloc((size_t)kRows*kD*4);
  u16*   tbf   = (u16*)  alloc((size_t)kRows*kD*2);
  float* coef  = (float*)alloc((size_t)kRows*kE*4);
  int*   counts= (int*)  alloc(kE*4);
  int*   lists = (int*)  alloc((size_t)kE*kRows*4);
  f16*   Bqh   = (f16*)  alloc((size_t)kQKVN*kD*2);
  f16*   Bql   = (f16*)  alloc((size_t)kQKVN*kD*2);
  f16*   Bwh   = (f16*)  alloc((size_t)kD*kD*2);
  f16*   Bwl   = (f16*)  alloc((size_t)kD*kD*2);
  u16*   w1t   = (u16*)  alloc((size_t)kHID*kD*2);
  u16*   w3t   = (u16*)  alloc((size_t)kHID*kD*2);
  u16*   w2t   = (u16*)  alloc((size_t)kD*kHID*2);
  u16*   hid   = (u16*)  alloc((size_t)kRows*kHID*2);

  // ---- weight prep: transpose + f16-split ----
  transpose_split_kernel<<<dim3(kD/32, kD/32), dim3(32,8), 0, stream>>>(wq, Bqh, Bql, kD, 2048, 0, kD);
  transpose_split_kernel<<<dim3(512/32, kD/32), dim3(32,8), 0, stream>>>(wk, Bqh, Bql, kD, 512, 2048, kD);
  transpose_split_kernel<<<dim3(512/32, kD/32), dim3(32,8), 0, stream>>>(wv, Bqh, Bql, kD, 512, 2560, kD);
  transpose_split_kernel<<<dim3(kD/32, kD/32), dim3(32,8), 0, stream>>>(wo, Bwh, Bwl, kD, kD, 0, kD);

  // ---- attention path (f32-equivalent precision, split-f16 MFMA) ----
  rms_f32_kernel<<<kRows, 256, 0, stream>>>(x, anw, h32);
  gemm_sf16_kernel<false><<<dim3(kQKVN/128, kRows/128), 256, 0, stream>>>(
      h32, kD, Bqh, Bql, qkv, kQKVN, 0, nullptr, 0, kD);
  rope_kernel<<<(kB*kS*(kH+kKVH)*(kHD/2))/256, 256, 0, stream>>>(qkv, fcos, fsin);
  vt_transpose_kernel<<<dim3(kS/32, (kKVH*kHD)/32, kB), dim3(32,8), 0, stream>>>(qkv, vTb);
  attn_sf16_kernel<<<dim3(kS/64, kH, kB), 256, 0, stream>>>(qkv, vTb, attno);
  gemm_sf16_kernel<true><<<dim3(kD/128, kRows/128), 256, 0, stream>>>(
      attno, kD, Bwh, Bwl, outp, kD, 0, x, kD, kD);

  // ---- gate (f32, from exact h1 in d_out) ----
  zero_counts_kernel<<<1, 64, 0, stream>>>(counts);
  gate_kernel<<<kRows, 64, 0, stream>>>(outp, fnw, gw, coef, lists, counts);
  rms_bf16_kernel<<<kRows, 256, 0, stream>>>(outp, fnw, tbf);

  // ---- MoE: bf16 MFMA per expert, d_out += coef * ff ----
  for (int e = 0; e < kE; ++e) {
    transpose_bf16_kernel<<<dim3(kHID/32, kD/32), dim3(32,8), 0, stream>>>(
        w1 + (size_t)e*kD*kHID, w1t, kD, kHID);
    transpose_bf16_kernel<<<dim3(kHID/32, kD/32), dim3(32,8), 0, stream>>>(
        w3 + (size_t)e*kD*kHID, w3t, kD, kHID);
    transpose_bf16_kernel<<<dim3(kD/32, kHID/32), dim3(32,8), 0, stream>>>(
        w2 + (size_t)e*kHID*kD, w2t, kHID, kD);
    gemm_w1w3_kernel<<<dim3(kHID/128, kRows/128), 256, 0, stream>>>(
        tbf, w1t, w3t, hid, lists + e*kRows, counts + e, kD);
    gemm_w2_kernel<<<dim3(kD/128, kRows/128), 256, 0, stream>>>(
        hid, kHID, w2t, outp, kD, lists + e*kRows, counts + e, coef, e, kHID);
  }
}

// Round 3
// 1170.434 us; speedup vs baseline: 3.2429x; 1.8304x over previous
//
#include <hip/hip_runtime.h>

typedef unsigned short u16;
typedef unsigned int u32;
typedef __bf16 bf16x8 __attribute__((ext_vector_type(8)));
typedef _Float16 f16;
typedef f16 f16x8 __attribute__((ext_vector_type(8)));
typedef float f32x4 __attribute__((ext_vector_type(4)));

#define DEVFN __device__ __forceinline__

constexpr int kB = 2, kS = 1024, kD = 2048, kH = 16, kKVH = 4, kHD = 128;
constexpr int kHID = 4096, kE = 8;
constexpr int kRows = kB * kS;               // 2048 tokens
constexpr int kQKVN = kH*kHD + 2*kKVH*kHD;   // 3072 fused qkv cols
constexpr int kSlots = 2 * kRows;            // 4096
constexpr float kEps = 1e-5f;
constexpr float kNeg = -1000000000.0f;
constexpr float kScale = 0.08838834764831845f;

DEVFN u16 f2bf(float f) {
  u32 u = __float_as_uint(f);
  return (u16)((u + 0x7fffu + ((u >> 16) & 1u)) >> 16);
}
DEVFN float bf2f(u16 u) { u32 v = ((u32)u) << 16; return __uint_as_float(v); }

DEVFN void split8v(float4 a, float4 b, f16x8& hi, f16x8& lo) {
  float v[8] = {a.x, a.y, a.z, a.w, b.x, b.y, b.z, b.w};
  #pragma unroll
  for (int e = 0; e < 8; ++e) {
    f16 h = (f16)v[e];
    hi[e] = h;
    lo[e] = (f16)(v[e] - (float)h);
  }
}

DEVFN void gll16(const void* g, void* l) {
  __builtin_amdgcn_global_load_lds(
      (const __attribute__((address_space(1))) void*)g,
      (__attribute__((address_space(3))) void*)l, 16, 0, 0);
}

// ---------------- RMSNorm + f16 split ----------------
__global__ __launch_bounds__(256) void rms_split_kernel(const float* __restrict__ in,
    const float* __restrict__ w, f16* __restrict__ oh, f16* __restrict__ ol) {
  int row = blockIdx.x, tid = threadIdx.x;
  const float* x = in + (size_t)row * kD;
  float4 v0 = *(const float4*)&x[tid*8];
  float4 v1 = *(const float4*)&x[tid*8+4];
  float ss = v0.x*v0.x+v0.y*v0.y+v0.z*v0.z+v0.w*v0.w
           + v1.x*v1.x+v1.y*v1.y+v1.z*v1.z+v1.w*v1.w;
  #pragma unroll
  for (int off = 32; off; off >>= 1) ss += __shfl_xor(ss, off);
  __shared__ float red[4];
  if ((tid & 63) == 0) red[tid >> 6] = ss;
  __syncthreads();
  float tot = red[0] + red[1] + red[2] + red[3];
  float rs = rsqrtf(tot * (1.0f/kD) + kEps);
  float4 w0 = *(const float4*)&w[tid*8];
  float4 w1 = *(const float4*)&w[tid*8+4];
  float4 o0, o1;
  o0.x = v0.x*rs*w0.x; o0.y = v0.y*rs*w0.y; o0.z = v0.z*rs*w0.z; o0.w = v0.w*rs*w0.w;
  o1.x = v1.x*rs*w1.x; o1.y = v1.y*rs*w1.y; o1.z = v1.z*rs*w1.z; o1.w = v1.w*rs*w1.w;
  f16x8 hi, lo;
  split8v(o0, o1, hi, lo);
  *(f16x8*)&oh[(size_t)row*kD + tid*8] = hi;
  *(f16x8*)&ol[(size_t)row*kD + tid*8] = lo;
}

__global__ __launch_bounds__(256) void split_kernel(const float* __restrict__ in,
    f16* __restrict__ oh, f16* __restrict__ ol, int n8) {
  int i = blockIdx.x * 256 + threadIdx.x;
  if (i >= n8) return;
  float4 a = *(const float4*)&in[i*8];
  float4 b = *(const float4*)&in[i*8+4];
  f16x8 hi, lo;
  split8v(a, b, hi, lo);
  *(f16x8*)&oh[i*8] = hi;
  *(f16x8*)&ol[i*8] = lo;
}

__global__ __launch_bounds__(256) void rms_bf16_kernel(const float* __restrict__ in,
    const float* __restrict__ w, u16* __restrict__ out) {
  int row = blockIdx.x, tid = threadIdx.x;
  const float* x = in + (size_t)row * kD;
  float4 v0 = *(const float4*)&x[tid*8];
  float4 v1 = *(const float4*)&x[tid*8+4];
  float ss = v0.x*v0.x+v0.y*v0.y+v0.z*v0.z+v0.w*v0.w
           + v1.x*v1.x+v1.y*v1.y+v1.z*v1.z+v1.w*v1.w;
  #pragma unroll
  for (int off = 32; off; off >>= 1) ss += __shfl_xor(ss, off);
  __shared__ float red[4];
  if ((tid & 63) == 0) red[tid >> 6] = ss;
  __syncthreads();
  float tot = red[0] + red[1] + red[2] + red[3];
  float rs = rsqrtf(tot * (1.0f/kD) + kEps);
  float4 w0 = *(const float4*)&w[tid*8];
  float4 w1 = *(const float4*)&w[tid*8+4];
  union { int4 i4; u16 u[8]; } pk;
  pk.u[0] = f2bf(v0.x*rs*w0.x); pk.u[1] = f2bf(v0.y*rs*w0.y);
  pk.u[2] = f2bf(v0.z*rs*w0.z); pk.u[3] = f2bf(v0.w*rs*w0.w);
  pk.u[4] = f2bf(v1.x*rs*w1.x); pk.u[5] = f2bf(v1.y*rs*w1.y);
  pk.u[6] = f2bf(v1.z*rs*w1.z); pk.u[7] = f2bf(v1.w*rs*w1.w);
  *(int4*)&out[(size_t)row*kD + tid*8] = pk.i4;
}

__global__ void transpose_split_kernel(const float* __restrict__ in,
    f16* __restrict__ hi, f16* __restrict__ lo, int R, int C, int noff, int ldout) {
  __shared__ float tile[32][33];
  int c0 = blockIdx.x * 32, r0 = blockIdx.y * 32;
  int tx = threadIdx.x, ty = threadIdx.y;
  #pragma unroll
  for (int i = 0; i < 32; i += 8)
    tile[ty + i][tx] = in[(size_t)(r0 + ty + i) * C + c0 + tx];
  __syncthreads();
  #pragma unroll
  for (int i = 0; i < 32; i += 8) {
    float v = tile[tx][ty + i];
    f16 h = (f16)v;
    size_t o = (size_t)(noff + c0 + ty + i) * ldout + r0 + tx;
    hi[o] = h;
    lo[o] = (f16)(v - (float)h);
  }
}

__global__ void vt_transpose_kernel(const float* __restrict__ qkv, float* __restrict__ vT) {
  __shared__ float tile[32][33];
  int s0 = blockIdx.x * 32, c0 = blockIdx.y * 32, b = blockIdx.z;
  int tx = threadIdx.x, ty = threadIdx.y;
  #pragma unroll
  for (int i = 0; i < 32; i += 8)
    tile[ty + i][tx] = qkv[(size_t)(b*kS + s0 + ty + i) * kQKVN + kH*kHD + kKVH*kHD + c0 + tx];
  __syncthreads();
  #pragma unroll
  for (int i = 0; i < 32; i += 8)
    vT[(size_t)(b*kKVH*kHD + c0 + ty + i) * kS + s0 + tx] = tile[tx][ty + i];
}

__global__ void transpose_bf16_kernel(const float* __restrict__ in,
    u16* __restrict__ out, int R, int C) {
  __shared__ float tile[32][33];
  int c0 = blockIdx.x * 32, r0 = blockIdx.y * 32;
  int tx = threadIdx.x, ty = threadIdx.y;
  #pragma unroll
  for (int i = 0; i < 32; i += 8)
    tile[ty + i][tx] = in[(size_t)(r0 + ty + i) * C + c0 + tx];
  __syncthreads();
  #pragma unroll
  for (int i = 0; i < 32; i += 8)
    out[(size_t)(c0 + ty + i) * R + r0 + tx] = f2bf(tile[tx][ty + i]);
}

// ---------------- split-f16 GEMM via global_load_lds ----------------
template<bool ADDX>
__global__ __launch_bounds__(256) void gemm_sf16_kernel(
    const f16* __restrict__ Ah0, const f16* __restrict__ Al0, int lda,
    const f16* __restrict__ Bh0, const f16* __restrict__ Bl0,
    float* __restrict__ C, int ldc, int coff,
    const float* __restrict__ X, int ldx, int K) {
  __shared__ __align__(16) u16 Ah[128*64], Al[128*64], Bh[128*64], Bl[128*64];
  int tid = threadIdx.x, lane = tid & 63, w = tid >> 6;
  int bm = blockIdx.y * 128, bn = blockIdx.x * 128;
  int wr = w >> 1, wc = w & 1;
  int hg = lane >> 4, lid = lane & 15;
  f32x4 acc[4][4] = {};
  const f16 *aH[4], *aL[4], *bH[4], *bL[4];
  #pragma unroll
  for (int j = 0; j < 4; ++j) {
    int r = w*32 + j*8 + (lane >> 3);
    int colc = ((lane & 7) ^ (r & 7)) * 8;
    aH[j] = Ah0 + (size_t)(bm + r) * lda + colc;
    aL[j] = Al0 + (size_t)(bm + r) * lda + colc;
    bH[j] = Bh0 + (size_t)(bn + r) * K + colc;
    bL[j] = Bl0 + (size_t)(bn + r) * K + colc;
  }
  const char* AhB = (const char*)Ah; const char* AlB = (const char*)Al;
  const char* BhB = (const char*)Bh; const char* BlB = (const char*)Bl;
  for (int kt = 0; kt < K; kt += 64) {
    __syncthreads();
    #pragma unroll
    for (int j = 0; j < 4; ++j) {
      int lb = w*2048 + j*512;
      gll16(aH[j] + kt, &Ah[lb]);
      gll16(aL[j] + kt, &Al[lb]);
      gll16(bH[j] + kt, &Bh[lb]);
      gll16(bL[j] + kt, &Bl[lb]);
    }
    __syncthreads();
    #pragma unroll
    for (int kk = 0; kk < 2; ++kk) {
      f16x8 ah[4], al[4], bh[4], bl[4];
      #pragma unroll
      for (int f = 0; f < 4; ++f) {
        int rA = wr*64 + f*16 + lid;
        int oA = (rA*128 + kk*64 + hg*16) ^ ((rA & 7) << 4);
        ah[f] = *(const f16x8*)(AhB + oA);
        al[f] = *(const f16x8*)(AlB + oA);
        int rB = wc*64 + f*16 + lid;
        int oB = (rB*128 + kk*64 + hg*16) ^ ((rB & 7) << 4);
        bh[f] = *(const f16x8*)(BhB + oB);
        bl[f] = *(const f16x8*)(BlB + oB);
      }
      #pragma unroll
      for (int i = 0; i < 4; ++i)
        #pragma unroll
        for (int j = 0; j < 4; ++j) {
          acc[i][j] = __builtin_amdgcn_mfma_f32_16x16x32_f16(ah[i], bh[j], acc[i][j], 0, 0, 0);
          acc[i][j] = __builtin_amdgcn_mfma_f32_16x16x32_f16(ah[i], bl[j], acc[i][j], 0, 0, 0);
          acc[i][j] = __builtin_amdgcn_mfma_f32_16x16x32_f16(al[i], bh[j], acc[i][j], 0, 0, 0);
        }
    }
  }
  #pragma unroll
  for (int i = 0; i < 4; ++i) {
    #pragma unroll
    for (int rr = 0; rr < 4; ++rr) {
      size_t gr = (size_t)(bm + wr*64 + i*16 + hg*4 + rr);
      #pragma unroll
      for (int j = 0; j < 4; ++j) {
        int gc = bn + wc*64 + j*16 + lid;
        float v = acc[i][j][rr];
        if (ADDX) v += X[gr * ldx + gc];
        C[gr * ldc + coff + gc] = v;
      }
    }
  }
}

// ---------------- RoPE ----------------
__global__ __launch_bounds__(256) void rope_kernel(float* __restrict__ qkv,
    const float* __restrict__ fc, const float* __restrict__ fs) {
  int idx = blockIdx.x * 256 + threadIdx.x;
  constexpr int NQ = kB*kS*kH*(kHD/2);
  constexpr int NK = kB*kS*kKVH*(kHD/2);
  size_t base; int s, i;
  if (idx < NQ) {
    i = idx & 63; int h = (idx >> 6) & 15; s = (idx >> 10) & 1023; int b = idx >> 20;
    base = ((size_t)(b*kS + s))*kQKVN + h*kHD + 2*i;
  } else {
    int j = idx - NQ; if (j >= NK) return;
    i = j & 63; int h = (j >> 6) & 3; s = (j >> 8) & 1023; int b = j >> 18;
    base = ((size_t)(b*kS + s))*kQKVN + kH*kHD + h*kHD + 2*i;
  }
  float c = fc[s*64 + i], sn = fs[s*64 + i];
  float xr = qkv[base], xi = qkv[base+1];
  qkv[base]   = xr*c - xi*sn;
  qkv[base+1] = xr*sn + xi*c;
}

// ---------------- split-f16 MFMA flash attention ----------------
__global__ __launch_bounds__(256) void attn_sf16_kernel(const float* __restrict__ qkv,
    const float* __restrict__ vT, float* __restrict__ out) {
  int qt = (int)gridDim.x - 1 - blockIdx.x;
  int h = blockIdx.y, b = blockIdx.z;
  int kvh = h >> 2;
  int q0 = qt * 64;
  __shared__ __align__(16) char Kh[64*128*2], Kl[64*128*2];
  __shared__ __align__(16) char Vh[128*64*2], Vl[128*64*2];
  __shared__ __align__(16) char Ph[4][16*64*2], Pl[4][16*64*2];
  int tid = threadIdx.x, lane = tid & 63, w = tid >> 6;
  int hg = lane >> 4, lid = lane & 15;

  f16x8 qh[4], ql[4];
  {
    const float* qrow = qkv + (size_t)(b*kS + q0 + w*16 + lid) * kQKVN + h*kHD;
    #pragma unroll
    for (int ks = 0; ks < 4; ++ks) {
      float4 a = *(const float4*)(qrow + ks*32 + hg*8);
      float4 c = *(const float4*)(qrow + ks*32 + hg*8 + 4);
      split8v(a, c, qh[ks], ql[ks]);
    }
  }
  f32x4 oacc[8] = {};
  float m[4] = {-3.0e38f, -3.0e38f, -3.0e38f, -3.0e38f};
  float lsum[4] = {};
  char* Phw = Ph[w];
  char* Plw = Pl[w];

  for (int kt = 0; kt <= qt; ++kt) {
    __syncthreads();
    {
      int r = tid >> 2, c0 = (tid & 3) * 32;
      const float* kr = qkv + (size_t)(b*kS + kt*64 + r) * kQKVN + kH*kHD + kvh*kHD + c0;
      #pragma unroll
      for (int s8 = 0; s8 < 4; ++s8) {
        float4 a = *(const float4*)(kr + s8*8);
        float4 c = *(const float4*)(kr + s8*8 + 4);
        f16x8 hi, lo; split8v(a, c, hi, lo);
        int off = (r*256 + c0*2 + s8*16) ^ ((r & 7) << 4);
        *(f16x8*)(Kh + off) = hi;
        *(f16x8*)(Kl + off) = lo;
      }
    }
    {
      int r = tid >> 1, c0 = (tid & 1) * 32;
      const float* vr = vT + (size_t)(b*kKVH*kHD + kvh*kHD + r) * kS + kt*64 + c0;
      #pragma unroll
      for (int s8 = 0; s8 < 4; ++s8) {
        float4 a = *(const float4*)(vr + s8*8);
        float4 c = *(const float4*)(vr + s8*8 + 4);
        f16x8 hi, lo; split8v(a, c, hi, lo);
        int off = (r*128 + c0*2 + s8*16) ^ ((r & 7) << 4);
        *(f16x8*)(Vh + off) = hi;
        *(f16x8*)(Vl + off) = lo;
      }
    }
    __syncthreads();

    f32x4 sacc[4] = {};
    #pragma unroll
    for (int ks = 0; ks < 4; ++ks) {
      #pragma unroll
      for (int j = 0; j < 4; ++j) {
        int rB = j*16 + lid;
        int off = (rB*256 + ks*64 + hg*16) ^ ((rB & 7) << 4);
        f16x8 kh = *(const f16x8*)(Kh + off);
        f16x8 klo = *(const f16x8*)(Kl + off);
        sacc[j] = __builtin_amdgcn_mfma_f32_16x16x32_f16(qh[ks], kh, sacc[j], 0, 0, 0);
        sacc[j] = __builtin_amdgcn_mfma_f32_16x16x32_f16(qh[ks], klo, sacc[j], 0, 0, 0);
        sacc[j] = __builtin_amdgcn_mfma_f32_16x16x32_f16(ql[ks], kh, sacc[j], 0, 0, 0);
      }
    }
    float s[4][4], ps[4][4];
    bool diag = (kt == qt);
    #pragma unroll
    for (int j = 0; j < 4; ++j)
      #pragma unroll
      for (int r = 0; r < 4; ++r) {
        float v = sacc[j][r] * kScale;
        if (diag) {
          int kvabs = kt*64 + j*16 + lid;
          int qabs = q0 + w*16 + hg*4 + r;
          if (kvabs > qabs) v = kNeg;
        }
        s[j][r] = v;
      }
    float pm[4], cf[4];
    #pragma unroll
    for (int r = 0; r < 4; ++r) {
      pm[r] = fmaxf(fmaxf(s[0][r], s[1][r]), fmaxf(s[2][r], s[3][r]));
      #pragma unroll
      for (int msk = 1; msk < 16; msk <<= 1) pm[r] = fmaxf(pm[r], __shfl_xor(pm[r], msk));
      float mn = fmaxf(m[r], pm[r]);
      cf[r] = __expf(m[r] - mn);
      m[r] = mn;
    }
    #pragma unroll
    for (int j2 = 0; j2 < 8; ++j2)
      #pragma unroll
      for (int r = 0; r < 4; ++r) oacc[j2][r] *= cf[r];
    float rs[4] = {};
    #pragma unroll
    for (int j = 0; j < 4; ++j)
      #pragma unroll
      for (int r = 0; r < 4; ++r) {
        float p = __expf(s[j][r] - m[r]);
        ps[j][r] = p;
        rs[r] += p;
      }
    #pragma unroll
    for (int r = 0; r < 4; ++r) lsum[r] = lsum[r]*cf[r] + rs[r];
    #pragma unroll
    for (int j = 0; j < 4; ++j)
      #pragma unroll
      for (int r = 0; r < 4; ++r) {
        int q = hg*4 + r;
        int off = (q*128 + (j*16 + lid)*2) ^ ((q & 7) << 4);
        f16 ph = (f16)ps[j][r];
        *(f16*)(Phw + off) = ph;
        *(f16*)(Plw + off) = (f16)(ps[j][r] - (float)ph);
      }
    #pragma unroll
    for (int kk2 = 0; kk2 < 2; ++kk2) {
      int oP = (lid*128 + kk2*64 + hg*16) ^ ((lid & 7) << 4);
      f16x8 pa_h = *(const f16x8*)(Phw + oP);
      f16x8 pa_l = *(const f16x8*)(Plw + oP);
      #pragma unroll
      for (int j2 = 0; j2 < 8; ++j2) {
        int rV = j2*16 + lid;
        int off = (rV*128 + kk2*64 + hg*16) ^ ((rV & 7) << 4);
        f16x8 vh = *(const f16x8*)(Vh + off);
        f16x8 vl = *(const f16x8*)(Vl + off);
        oacc[j2] = __builtin_amdgcn_mfma_f32_16x16x32_f16(pa_h, vh, oacc[j2], 0, 0, 0);
        oacc[j2] = __builtin_amdgcn_mfma_f32_16x16x32_f16(pa_h, vl, oacc[j2], 0, 0, 0);
        oacc[j2] = __builtin_amdgcn_mfma_f32_16x16x32_f16(pa_l, vh, oacc[j2], 0, 0, 0);
      }
    }
  }
  #pragma unroll
  for (int r = 0; r < 4; ++r) {
    #pragma unroll
    for (int msk = 1; msk < 16; msk <<= 1) lsum[r] += __shfl_xor(lsum[r], msk);
    lsum[r] = 1.f / lsum[r];
  }
  #pragma unroll
  for (int j2 = 0; j2 < 8; ++j2)
    #pragma unroll
    for (int r = 0; r < 4; ++r) {
      size_t o = (size_t)(b*kS + q0 + w*16 + hg*4 + r) * kD + h*kHD + j2*16 + lid;
      out[o] = oacc[j2][r] * lsum[r];
    }
}

// ---------------- gate / prefix ----------------
__global__ void zero_counts_kernel(int* counts) {
  if (threadIdx.x < kE) counts[threadIdx.x] = 0;
}

__global__ __launch_bounds__(64) void gate_kernel(const float* __restrict__ h1,
    const float* __restrict__ wn, const float* __restrict__ gw,
    int* __restrict__ packA, int* __restrict__ packB,
    float* __restrict__ cA, float* __restrict__ cB,
    int* __restrict__ lists, int* __restrict__ counts) {
  int row = blockIdx.x, lane = threadIdx.x;
  const float* x = h1 + (size_t)row * kD;
  float ss = 0.f;
  for (int d = lane; d < kD; d += 64) { float v = x[d]; ss = fmaf(v, v, ss); }
  #pragma unroll
  for (int off = 32; off; off >>= 1) ss += __shfl_xor(ss, off);
  float rs = rsqrtf(ss * (1.0f/kD) + kEps);
  float acc[kE] = {};
  for (int d = lane; d < kD; d += 64) {
    float g = x[d] * rs * wn[d];
    const float* gr = gw + (size_t)d * kE;
    #pragma unroll
    for (int e = 0; e < kE; ++e) acc[e] = fmaf(g, gr[e], acc[e]);
  }
  #pragma unroll
  for (int e = 0; e < kE; ++e)
    #pragma unroll
    for (int off = 32; off; off >>= 1) acc[e] += __shfl_xor(acc[e], off);
  if (lane == 0) {
    int i1 = 0; float l1 = acc[0];
    #pragma unroll
    for (int e = 1; e < kE; ++e) if (acc[e] > l1) { l1 = acc[e]; i1 = e; }
    int i2 = -1; float l2 = -3.4e38f;
    #pragma unroll
    for (int e = 0; e < kE; ++e) if (e != i1 && acc[e] > l2) { l2 = acc[e]; i2 = e; }
    float e2 = __expf(l2 - l1);
    float inv = 1.f / (1.f + e2);
    int p1 = atomicAdd(&counts[i1], 1); lists[i1*kRows + p1] = row;
    int p2 = atomicAdd(&counts[i2], 1); lists[i2*kRows + p2] = row;
    packA[row] = i1*2048 + p1; cA[row] = inv;
    packB[row] = i2*2048 + p2; cB[row] = e2 * inv;
  }
}

__global__ void prefix_kernel(const int* __restrict__ counts, int* __restrict__ prefix) {
  if (threadIdx.x == 0) {
    int s = 0;
    for (int e = 0; e < kE; ++e) { prefix[e] = s; s += counts[e]; }
  }
}

// ------- batched MoE up-proj: all experts in one dispatch -------
__global__ __launch_bounds__(256) void gemm_w1w3_kernel(
    const u16* __restrict__ A, const u16* __restrict__ W1T, const u16* __restrict__ W3T,
    u16* __restrict__ hid, const int* __restrict__ lists,
    const int* __restrict__ counts, const int* __restrict__ prefix) {
  int e = blockIdx.y >> 4, mb = blockIdx.y & 15;
  int cnt = counts[e];
  int bm = mb * 128;
  if (bm >= cnt) return;
  int slotbase = prefix[e];
  const int* ids = lists + e * kRows;
  const u16* B1t = W1T + (size_t)e * kHID * kD;
  const u16* B3t = W3T + (size_t)e * kHID * kD;
  int bn = blockIdx.x * 128;
  __shared__ __align__(16) u16 As[128*64], B1s[128*64], B3s[128*64];
  int tid = threadIdx.x, lane = tid & 63, w = tid >> 6;
  int wr = w >> 1, wc = w & 1;
  int hg = lane >> 4, lid = lane & 15;
  f32x4 acc1[4][4] = {}, acc3[4][4] = {};
  const u16 *aP[4], *b1P[4], *b3P[4];
  #pragma unroll
  for (int j = 0; j < 4; ++j) {
    int r = w*32 + j*8 + (lane >> 3);
    int colc = ((lane & 7) ^ (r & 7)) * 8;
    int rr = bm + r; if (rr >= cnt) rr = cnt - 1;
    aP[j]  = A + (size_t)ids[rr] * kD + colc;
    b1P[j] = B1t + (size_t)(bn + r) * kD + colc;
    b3P[j] = B3t + (size_t)(bn + r) * kD + colc;
  }
  const char* AsB = (const char*)As;
  const char* B1B = (const char*)B1s;
  const char* B3B = (const char*)B3s;
  for (int kt = 0; kt < kD; kt += 64) {
    __syncthreads();
    #pragma unroll
    for (int j = 0; j < 4; ++j) {
      int lb = w*2048 + j*512;
      gll16(aP[j] + kt, &As[lb]);
      gll16(b1P[j] + kt, &B1s[lb]);
      gll16(b3P[j] + kt, &B3s[lb]);
    }
    __syncthreads();
    #pragma unroll
    for (int kk = 0; kk < 2; ++kk) {
      bf16x8 af[4], b1f[4], b3f[4];
      #pragma unroll
      for (int f = 0; f < 4; ++f) {
        int rA = wr*64 + f*16 + lid;
        af[f] = *(const bf16x8*)(AsB + ((rA*128 + kk*64 + hg*16) ^ ((rA & 7) << 4)));
        int rB = wc*64 + f*16 + lid;
        int oB = (rB*128 + kk*64 + hg*16) ^ ((rB & 7) << 4);
        b1f[f] = *(const bf16x8*)(B1B + oB);
        b3f[f] = *(const bf16x8*)(B3B + oB);
      }
      #pragma unroll
      for (int i = 0; i < 4; ++i)
        #pragma unroll
        for (int j = 0; j < 4; ++j) {
          acc1[i][j] = __builtin_amdgcn_mfma_f32_16x16x32_bf16(af[i], b1f[j], acc1[i][j], 0, 0, 0);
          acc3[i][j] = __builtin_amdgcn_mfma_f32_16x16x32_bf16(af[i], b3f[j], acc3[i][j], 0, 0, 0);
        }
    }
  }
  #pragma unroll
  for (int i = 0; i < 4; ++i) {
    #pragma unroll
    for (int rr = 0; rr < 4; ++rr) {
      int gr = bm + wr*64 + i*16 + hg*4 + rr;
      if (gr >= cnt) continue;
      #pragma unroll
      for (int j = 0; j < 4; ++j) {
        int gc = bn + wc*64 + j*16 + lid;
        float a1 = acc1[i][j][rr], a3 = acc3[i][j][rr];
        float hv = a1 / (1.f + __expf(-a1)) * a3;
        hid[(size_t)(slotbase + gr) * kHID + gc] = f2bf(hv);
      }
    }
  }
}

// ------- batched MoE down-proj -------
__global__ __launch_bounds__(256) void gemm_w2_kernel(
    const u16* __restrict__ hid, const u16* __restrict__ W2T,
    u16* __restrict__ ff, const int* __restrict__ counts, const int* __restrict__ prefix) {
  int e = blockIdx.y >> 4, mb = blockIdx.y & 15;
  int cnt = counts[e];
  int bm = mb * 128;
  if (bm >= cnt) return;
  int slotbase = prefix[e];
  const u16* B2t = W2T + (size_t)e * kD * kHID;
  int bn = blockIdx.x * 128;
  __shared__ __align__(16) u16 As[128*64], Bs[128*64];
  int tid = threadIdx.x, lane = tid & 63, w = tid >> 6;
  int wr = w >> 1, wc = w & 1;
  int hg = lane >> 4, lid = lane & 15;
  f32x4 acc[4][4] = {};
  const u16 *aP[4], *bP[4];
  #pragma unroll
  for (int j = 0; j < 4; ++j) {
    int r = w*32 + j*8 + (lane >> 3);
    int colc = ((lane & 7) ^ (r & 7)) * 8;
    int rr = bm + r; if (rr >= cnt) rr = cnt - 1;
    aP[j] = hid + (size_t)(slotbase + rr) * kHID + colc;
    bP[j] = B2t + (size_t)(bn + r) * kHID + colc;
  }
  const char* AsB = (const char*)As;
  const char* BsB = (const char*)Bs;
  for (int kt = 0; kt < kHID; kt += 64) {
    __syncthreads();
    #pragma unroll
    for (int j = 0; j < 4; ++j) {
      int lb = w*2048 + j*512;
      gll16(aP[j] + kt, &As[lb]);
      gll16(bP[j] + kt, &Bs[lb]);
    }
    __syncthreads();
    #pragma unroll
    for (int kk = 0; kk < 2; ++kk) {
      bf16x8 af[4], bfv[4];
      #pragma unroll
      for (int f = 0; f < 4; ++f) {
        int rA = wr*64 + f*16 + lid;
        af[f] = *(const bf16x8*)(AsB + ((rA*128 + kk*64 + hg*16) ^ ((rA & 7) << 4)));
        int rB = wc*64 + f*16 + lid;
        bfv[f] = *(const bf16x8*)(BsB + ((rB*128 + kk*64 + hg*16) ^ ((rB & 7) << 4)));
      }
      #pragma unroll
      for (int i = 0; i < 4; ++i)
        #pragma unroll
        for (int j = 0; j < 4; ++j)
          acc[i][j] = __builtin_amdgcn_mfma_f32_16x16x32_bf16(af[i], bfv[j], acc[i][j], 0, 0, 0);
    }
  }
  #pragma unroll
  for (int i = 0; i < 4; ++i) {
    #pragma unroll
    for (int rr = 0; rr < 4; ++rr) {
      int gr = bm + wr*64 + i*16 + hg*4 + rr;
      if (gr >= cnt) continue;
      #pragma unroll
      for (int j = 0; j < 4; ++j) {
        int gc = bn + wc*64 + j*16 + lid;
        ff[(size_t)(slotbase + gr) * kD + gc] = f2bf(acc[i][j][rr]);
      }
    }
  }
}

// ---------------- combine ----------------
__global__ __launch_bounds__(256) void moe_combine_kernel(
    const u16* __restrict__ ff, const int* __restrict__ prefix,
    const int* __restrict__ packA, const int* __restrict__ packB,
    const float* __restrict__ cA, const float* __restrict__ cB,
    float* __restrict__ outp) {
  int row = blockIdx.x, tid = threadIdx.x;
  int pa = packA[row], pb = packB[row];
  int sa = prefix[pa >> 11] + (pa & 2047);
  int sb = prefix[pb >> 11] + (pb & 2047);
  float ca = cA[row], cb = cB[row];
  union { int4 i4; u16 u[8]; } va, vb;
  va.i4 = *(const int4*)(ff + (size_t)sa * kD + tid*8);
  vb.i4 = *(const int4*)(ff + (size_t)sb * kD + tid*8);
  float* o = outp + (size_t)row * kD + tid*8;
  float4 o0 = *(const float4*)o;
  float4 o1 = *(const float4*)(o + 4);
  o0.x += ca*bf2f(va.u[0]) + cb*bf2f(vb.u[0]);
  o0.y += ca*bf2f(va.u[1]) + cb*bf2f(vb.u[1]);
  o0.z += ca*bf2f(va.u[2]) + cb*bf2f(vb.u[2]);
  o0.w += ca*bf2f(va.u[3]) + cb*bf2f(vb.u[3]);
  o1.x += ca*bf2f(va.u[4]) + cb*bf2f(vb.u[4]);
  o1.y += ca*bf2f(va.u[5]) + cb*bf2f(vb.u[5]);
  o1.z += ca*bf2f(va.u[6]) + cb*bf2f(vb.u[6]);
  o1.w += ca*bf2f(va.u[7]) + cb*bf2f(vb.u[7]);
  *(float4*)o = o0;
  *(float4*)(o + 4) = o1;
}

// ---------------- host launcher ----------------
extern "C" void kernel_launch(void* const* d_in, const int* in_sizes, int n_in,
                              void* d_out, int out_size, void* d_ws, size_t ws_size,
                              hipStream_t stream) {
  const float* x    = (const float*)d_in[0];
  const float* fcos = (const float*)d_in[1];
  const float* fsin = (const float*)d_in[2];
  const float* anw  = (const float*)d_in[5];
  const float* fnw  = (const float*)d_in[6];
  const float* wq   = (const float*)d_in[7];
  const float* wk   = (const float*)d_in[8];
  const float* wv   = (const float*)d_in[9];
  const float* wo   = (const float*)d_in[10];
  const float* gw   = (const float*)d_in[11];
  const float* w1   = (const float*)d_in[12];
  const float* w2   = (const float*)d_in[13];
  const float* w3   = (const float*)d_in[14];
  float* outp = (float*)d_out;

  char* ws = (char*)d_ws;
  size_t off = 0;
  auto alloc = [&](size_t bytes) -> void* {
    void* p = ws + off; off += (bytes + 255) & ~(size_t)255; return p;
  };
  f16* h16h   = (f16*)alloc((size_t)kRows*kD*2);
  f16* h16l   = (f16*)alloc((size_t)kRows*kD*2);
  float* qkv  = (float*)alloc((size_t)kRows*kQKVN*4);
  float* vTb  = (float*)alloc((size_t)kB*kKVH*kHD*kS*4);
  float* attno= (float*)alloc((size_t)kRows*kD*4);
  f16* a16h   = (f16*)alloc((size_t)kRows*kD*2);
  f16* a16l   = (f16*)alloc((size_t)kRows*kD*2);
  u16* tbf    = (u16*)alloc((size_t)kRows*kD*2);
  int* packA  = (int*)alloc(kRows*4);
  int* packB  = (int*)alloc(kRows*4);
  float* cAv  = (float*)alloc(kRows*4);
  float* cBv  = (float*)alloc(kRows*4);
  int* counts = (int*)alloc(kE*4);
  int* prefix = (int*)alloc(kE*4);
  int* lists  = (int*)alloc((size_t)kE*kRows*4);
  f16* Bqh    = (f16*)alloc((size_t)kQKVN*kD*2);
  f16* Bql    = (f16*)alloc((size_t)kQKVN*kD*2);
  f16* Bwh    = (f16*)alloc((size_t)kD*kD*2);
  f16* Bwl    = (f16*)alloc((size_t)kD*kD*2);
  u16* hid    = (u16*)alloc((size_t)kSlots*kHID*2);
  u16* ffb    = (u16*)alloc((size_t)kSlots*kD*2);
  u16* w1T    = (u16*)alloc((size_t)kE*kHID*kD*2);
  u16* w3T    = (u16*)alloc((size_t)kE*kHID*kD*2);
  u16* w2T    = (u16*)alloc((size_t)kE*kD*kHID*2);

  // ---- weight prep ----
  transpose_split_kernel<<<dim3(kD/32, kD/32), dim3(32,8), 0, stream>>>(wq, Bqh, Bql, kD, 2048, 0, kD);
  transpose_split_kernel<<<dim3(512/32, kD/32), dim3(32,8), 0, stream>>>(wk, Bqh, Bql, kD, 512, 2048, kD);
  transpose_split_kernel<<<dim3(512/32, kD/32), dim3(32,8), 0, stream>>>(wv, Bqh, Bql, kD, 512, 2560, kD);
  transpose_split_kernel<<<dim3(kD/32, kD/32), dim3(32,8), 0, stream>>>(wo, Bwh, Bwl, kD, kD, 0, kD);
  for (int e = 0; e < kE; ++e) {
    transpose_bf16_kernel<<<dim3(kHID/32, kD/32), dim3(32,8), 0, stream>>>(
        w1 + (size_t)e*kD*kHID, w1T + (size_t)e*kHID*kD, kD, kHID);
    transpose_bf16_kernel<<<dim3(kHID/32, kD/32), dim3(32,8), 0, stream>>>(
        w3 + (size_t)e*kD*kHID, w3T + (size_t)e*kHID*kD, kD, kHID);
    transpose_bf16_kernel<<<dim3(kD/32, kHID/32), dim3(32,8), 0, stream>>>(
        w2 + (size_t)e*kHID*kD, w2T + (size_t)e*kD*kHID, kHID, kD);
  }

  // ---- attention path ----
  rms_split_kernel<<<kRows, 256, 0, stream>>>(x, anw, h16h, h16l);
  gemm_sf16_kernel<false><<<dim3(kQKVN/128, kRows/128), 256, 0, stream>>>(
      h16h, h16l, kD, Bqh, Bql, qkv, kQKVN, 0, nullptr, 0, kD);
  rope_kernel<<<(kB*kS*(kH+kKVH)*(kHD/2))/256, 256, 0, stream>>>(qkv, fcos, fsin);
  vt_transpose_kernel<<<dim3(kS/32, (kKVH*kHD)/32, kB), dim3(32,8), 0, stream>>>(qkv, vTb);
  attn_sf16_kernel<<<dim3(kS/64, kH, kB), 256, 0, stream>>>(qkv, vTb, attno);
  split_kernel<<<(kRows*kD/8 + 255)/256, 256, 0, stream>>>(attno, a16h, a16l, kRows*kD/8);
  gemm_sf16_kernel<true><<<dim3(kD/128, kRows/128), 256, 0, stream>>>(
      a16h, a16l, kD, Bwh, Bwl, outp, kD, 0, x, kD, kD);

  // ---- gate ----
  zero_counts_kernel<<<1, 64, 0, stream>>>(counts);
  gate_kernel<<<kRows, 64, 0, stream>>>(outp, fnw, gw, packA, packB, cAv, cBv, lists, counts);
  prefix_kernel<<<1, 64, 0, stream>>>(counts, prefix);
  rms_bf16_kernel<<<kRows, 256, 0, stream>>>(outp, fnw, tbf);

  // ---- MoE: 2 batched dispatches + combine ----
  gemm_w1w3_kernel<<<dim3(kHID/128, kE*16), 256, 0, stream>>>(
      tbf, w1T, w3T, hid, lists, counts, prefix);
  gemm_w2_kernel<<<dim3(kD/128, kE*16), 256, 0, stream>>>(
      hid, w2T, ffb, counts, prefix);
  moe_combine_kernel<<<kRows, 256, 0, stream>>>(
      ffb, prefix, packA, packB, cAv, cBv, outp);
}

// Round 4
// 992.274 us; speedup vs baseline: 3.8251x; 1.1795x over previous
//
#include <hip/hip_runtime.h>

typedef unsigned short u16;
typedef unsigned int u32;
typedef __bf16 bf16x8 __attribute__((ext_vector_type(8)));
typedef _Float16 f16;
typedef f16 f16x8 __attribute__((ext_vector_type(8)));
typedef float f32x4 __attribute__((ext_vector_type(4)));

#define DEVFN __device__ __forceinline__

constexpr int kB = 2, kS = 1024, kD = 2048, kH = 16, kKVH = 4, kHD = 128;
constexpr int kHID = 4096, kE = 8;
constexpr int kRows = kB * kS;               // 2048 tokens
constexpr int kQKVN = kH*kHD + 2*kKVH*kHD;   // 3072 fused qkv cols
constexpr int kSlotsPad = 5120;              // 40 tiles x 128 (max padded slots)
constexpr int kMaxTiles = 40;
constexpr float kEps = 1e-5f;
constexpr float kNeg = -1000000000.0f;
constexpr float kScale = 0.08838834764831845f;

DEVFN u16 f2bf(float f) {
  u32 u = __float_as_uint(f);
  return (u16)((u + 0x7fffu + ((u >> 16) & 1u)) >> 16);
}
DEVFN float bf2f(u16 u) { u32 v = ((u32)u) << 16; return __uint_as_float(v); }

DEVFN void split8v(float4 a, float4 b, f16x8& hi, f16x8& lo) {
  float v[8] = {a.x, a.y, a.z, a.w, b.x, b.y, b.z, b.w};
  #pragma unroll
  for (int e = 0; e < 8; ++e) {
    f16 h = (f16)v[e];
    hi[e] = h;
    lo[e] = (f16)(v[e] - (float)h);
  }
}

DEVFN void gll16(const void* g, void* l) {
  __builtin_amdgcn_global_load_lds(
      (const __attribute__((address_space(1))) void*)g,
      (__attribute__((address_space(3))) void*)l, 16, 0, 0);
}

// ---------------- RMSNorm + f16 split ----------------
__global__ __launch_bounds__(256) void rms_split_kernel(const float* __restrict__ in,
    const float* __restrict__ w, f16* __restrict__ oh, f16* __restrict__ ol) {
  int row = blockIdx.x, tid = threadIdx.x;
  const float* x = in + (size_t)row * kD;
  float4 v0 = *(const float4*)&x[tid*8];
  float4 v1 = *(const float4*)&x[tid*8+4];
  float ss = v0.x*v0.x+v0.y*v0.y+v0.z*v0.z+v0.w*v0.w
           + v1.x*v1.x+v1.y*v1.y+v1.z*v1.z+v1.w*v1.w;
  #pragma unroll
  for (int off = 32; off; off >>= 1) ss += __shfl_xor(ss, off);
  __shared__ float red[4];
  if ((tid & 63) == 0) red[tid >> 6] = ss;
  __syncthreads();
  float tot = red[0] + red[1] + red[2] + red[3];
  float rs = rsqrtf(tot * (1.0f/kD) + kEps);
  float4 w0 = *(const float4*)&w[tid*8];
  float4 w1 = *(const float4*)&w[tid*8+4];
  float4 o0, o1;
  o0.x = v0.x*rs*w0.x; o0.y = v0.y*rs*w0.y; o0.z = v0.z*rs*w0.z; o0.w = v0.w*rs*w0.w;
  o1.x = v1.x*rs*w1.x; o1.y = v1.y*rs*w1.y; o1.z = v1.z*rs*w1.z; o1.w = v1.w*rs*w1.w;
  f16x8 hi, lo;
  split8v(o0, o1, hi, lo);
  *(f16x8*)&oh[(size_t)row*kD + tid*8] = hi;
  *(f16x8*)&ol[(size_t)row*kD + tid*8] = lo;
}

__global__ __launch_bounds__(256) void split_kernel(const float* __restrict__ in,
    f16* __restrict__ oh, f16* __restrict__ ol, int n8) {
  int i = blockIdx.x * 256 + threadIdx.x;
  if (i >= n8) return;
  float4 a = *(const float4*)&in[i*8];
  float4 b = *(const float4*)&in[i*8+4];
  f16x8 hi, lo;
  split8v(a, b, hi, lo);
  *(f16x8*)&oh[i*8] = hi;
  *(f16x8*)&ol[i*8] = lo;
}

__global__ __launch_bounds__(256) void rms_bf16_kernel(const float* __restrict__ in,
    const float* __restrict__ w, u16* __restrict__ out) {
  int row = blockIdx.x, tid = threadIdx.x;
  const float* x = in + (size_t)row * kD;
  float4 v0 = *(const float4*)&x[tid*8];
  float4 v1 = *(const float4*)&x[tid*8+4];
  float ss = v0.x*v0.x+v0.y*v0.y+v0.z*v0.z+v0.w*v0.w
           + v1.x*v1.x+v1.y*v1.y+v1.z*v1.z+v1.w*v1.w;
  #pragma unroll
  for (int off = 32; off; off >>= 1) ss += __shfl_xor(ss, off);
  __shared__ float red[4];
  if ((tid & 63) == 0) red[tid >> 6] = ss;
  __syncthreads();
  float tot = red[0] + red[1] + red[2] + red[3];
  float rs = rsqrtf(tot * (1.0f/kD) + kEps);
  float4 w0 = *(const float4*)&w[tid*8];
  float4 w1 = *(const float4*)&w[tid*8+4];
  union { int4 i4; u16 u[8]; } pk;
  pk.u[0] = f2bf(v0.x*rs*w0.x); pk.u[1] = f2bf(v0.y*rs*w0.y);
  pk.u[2] = f2bf(v0.z*rs*w0.z); pk.u[3] = f2bf(v0.w*rs*w0.w);
  pk.u[4] = f2bf(v1.x*rs*w1.x); pk.u[5] = f2bf(v1.y*rs*w1.y);
  pk.u[6] = f2bf(v1.z*rs*w1.z); pk.u[7] = f2bf(v1.w*rs*w1.w);
  *(int4*)&out[(size_t)row*kD + tid*8] = pk.i4;
}

// ------- transpose + f16-split (qkv/wo weights): f32 [R][C] -> hi/lo [C+noff][R] -------
__global__ void transpose_split_kernel(const float* __restrict__ in,
    f16* __restrict__ hi, f16* __restrict__ lo, int R, int C, int noff, int ldout) {
  __shared__ float tile[32][33];
  int c0 = blockIdx.x * 32, r0 = blockIdx.y * 32;
  int tx = threadIdx.x, ty = threadIdx.y;
  #pragma unroll
  for (int i = 0; i < 32; i += 8)
    tile[ty + i][tx] = in[(size_t)(r0 + ty + i) * C + c0 + tx];
  __syncthreads();
  #pragma unroll
  for (int i = 0; i < 32; i += 8) {
    float v = tile[tx][ty + i];
    f16 h = (f16)v;
    size_t o = (size_t)(noff + c0 + ty + i) * ldout + r0 + tx;
    hi[o] = h;
    lo[o] = (f16)(v - (float)h);
  }
}

// ------- batched w1/w3 transpose: f32 [2048][4096] -> wUT[e] rows (paired 64+64) -------
__global__ __launch_bounds__(256) void transpose_up_kernel(const float* __restrict__ w,
    u16* __restrict__ wUT, int half) {
  int e = blockIdx.z;
  const float* in = w + (size_t)e * kD * kHID;
  u16* out = wUT + (size_t)e * 8192 * kD;
  __shared__ float tile[64][69];
  int c0 = blockIdx.x * 64, r0 = blockIdx.y * 64;
  int tx = threadIdx.x & 15, ty = threadIdx.x >> 4;
  #pragma unroll
  for (int i = 0; i < 4; ++i) {
    float4 v = *(const float4*)&in[(size_t)(r0 + ty + i*16) * kHID + c0 + tx*4];
    tile[ty + i*16][tx*4+0] = v.x;
    tile[ty + i*16][tx*4+1] = v.y;
    tile[ty + i*16][tx*4+2] = v.z;
    tile[ty + i*16][tx*4+3] = v.w;
  }
  __syncthreads();
  int grp = c0 >> 6;
  #pragma unroll
  for (int i = 0; i < 4; ++i) {
    int cl = ty + i*16;
    int rowOut = grp*128 + cl + half*64;
    ushort4 o;
    o.x = f2bf(tile[tx*4+0][cl]);
    o.y = f2bf(tile[tx*4+1][cl]);
    o.z = f2bf(tile[tx*4+2][cl]);
    o.w = f2bf(tile[tx*4+3][cl]);
    *(ushort4*)&out[(size_t)rowOut * kD + r0 + tx*4] = o;
  }
}

// ------- batched w2 transpose: f32 [4096][2048] -> w2T[e] [2048][4096] bf16 -------
__global__ __launch_bounds__(256) void transpose_w2_kernel(const float* __restrict__ w,
    u16* __restrict__ w2T) {
  int e = blockIdx.z;
  const float* in = w + (size_t)e * kHID * kD;
  u16* out = w2T + (size_t)e * kD * kHID;
  __shared__ float tile[64][69];
  int c0 = blockIdx.x * 64, r0 = blockIdx.y * 64;
  int tx = threadIdx.x & 15, ty = threadIdx.x >> 4;
  #pragma unroll
  for (int i = 0; i < 4; ++i) {
    float4 v = *(const float4*)&in[(size_t)(r0 + ty + i*16) * kD + c0 + tx*4];
    tile[ty + i*16][tx*4+0] = v.x;
    tile[ty + i*16][tx*4+1] = v.y;
    tile[ty + i*16][tx*4+2] = v.z;
    tile[ty + i*16][tx*4+3] = v.w;
  }
  __syncthreads();
  #pragma unroll
  for (int i = 0; i < 4; ++i) {
    int cl = ty + i*16;
    ushort4 o;
    o.x = f2bf(tile[tx*4+0][cl]);
    o.y = f2bf(tile[tx*4+1][cl]);
    o.z = f2bf(tile[tx*4+2][cl]);
    o.w = f2bf(tile[tx*4+3][cl]);
    *(ushort4*)&out[(size_t)(c0 + cl) * kHID + r0 + tx*4] = o;
  }
}

// ------- V transpose + split: qkv V cols -> vTh/vTl [b][kvh*128+d][S] f16 -------
__global__ void vt_split_kernel(const float* __restrict__ qkv,
    f16* __restrict__ vTh, f16* __restrict__ vTl) {
  __shared__ float tile[32][33];
  int s0 = blockIdx.x * 32, c0 = blockIdx.y * 32, b = blockIdx.z;
  int tx = threadIdx.x, ty = threadIdx.y;
  #pragma unroll
  for (int i = 0; i < 32; i += 8)
    tile[ty + i][tx] = qkv[(size_t)(b*kS + s0 + ty + i) * kQKVN + kH*kHD + kKVH*kHD + c0 + tx];
  __syncthreads();
  #pragma unroll
  for (int i = 0; i < 32; i += 8) {
    float v = tile[tx][ty + i];
    f16 h = (f16)v;
    size_t o = (size_t)(b*kKVH*kHD + c0 + ty + i) * kS + s0 + tx;
    vTh[o] = h;
    vTl[o] = (f16)(v - (float)h);
  }
}

// ---------------- split-f16 GEMM via global_load_lds ----------------
template<bool ADDX>
__global__ __launch_bounds__(256) void gemm_sf16_kernel(
    const f16* __restrict__ Ah0, const f16* __restrict__ Al0, int lda,
    const f16* __restrict__ Bh0, const f16* __restrict__ Bl0,
    float* __restrict__ C, int ldc, int coff,
    const float* __restrict__ X, int ldx, int K) {
  __shared__ __align__(16) u16 Ah[128*64], Al[128*64], Bh[128*64], Bl[128*64];
  int tid = threadIdx.x, lane = tid & 63, w = tid >> 6;
  int bm = blockIdx.y * 128, bn = blockIdx.x * 128;
  int wr = w >> 1, wc = w & 1;
  int hg = lane >> 4, lid = lane & 15;
  f32x4 acc[4][4] = {};
  const f16 *aH[4], *aL[4], *bH[4], *bL[4];
  #pragma unroll
  for (int j = 0; j < 4; ++j) {
    int r = w*32 + j*8 + (lane >> 3);
    int colc = ((lane & 7) ^ (r & 7)) * 8;
    aH[j] = Ah0 + (size_t)(bm + r) * lda + colc;
    aL[j] = Al0 + (size_t)(bm + r) * lda + colc;
    bH[j] = Bh0 + (size_t)(bn + r) * K + colc;
    bL[j] = Bl0 + (size_t)(bn + r) * K + colc;
  }
  const char* AhB = (const char*)Ah; const char* AlB = (const char*)Al;
  const char* BhB = (const char*)Bh; const char* BlB = (const char*)Bl;
  for (int kt = 0; kt < K; kt += 64) {
    __syncthreads();
    #pragma unroll
    for (int j = 0; j < 4; ++j) {
      int lb = w*2048 + j*512;
      gll16(aH[j] + kt, &Ah[lb]);
      gll16(aL[j] + kt, &Al[lb]);
      gll16(bH[j] + kt, &Bh[lb]);
      gll16(bL[j] + kt, &Bl[lb]);
    }
    __syncthreads();
    #pragma unroll
    for (int kk = 0; kk < 2; ++kk) {
      f16x8 ah[4], al[4], bh[4], bl[4];
      #pragma unroll
      for (int f = 0; f < 4; ++f) {
        int rA = wr*64 + f*16 + lid;
        int oA = (rA*128 + kk*64 + hg*16) ^ ((rA & 7) << 4);
        ah[f] = *(const f16x8*)(AhB + oA);
        al[f] = *(const f16x8*)(AlB + oA);
        int rB = wc*64 + f*16 + lid;
        int oB = (rB*128 + kk*64 + hg*16) ^ ((rB & 7) << 4);
        bh[f] = *(const f16x8*)(BhB + oB);
        bl[f] = *(const f16x8*)(BlB + oB);
      }
      #pragma unroll
      for (int i = 0; i < 4; ++i)
        #pragma unroll
        for (int j = 0; j < 4; ++j) {
          acc[i][j] = __builtin_amdgcn_mfma_f32_16x16x32_f16(ah[i], bh[j], acc[i][j], 0, 0, 0);
          acc[i][j] = __builtin_amdgcn_mfma_f32_16x16x32_f16(ah[i], bl[j], acc[i][j], 0, 0, 0);
          acc[i][j] = __builtin_amdgcn_mfma_f32_16x16x32_f16(al[i], bh[j], acc[i][j], 0, 0, 0);
        }
    }
  }
  #pragma unroll
  for (int i = 0; i < 4; ++i) {
    #pragma unroll
    for (int rr = 0; rr < 4; ++rr) {
      size_t gr = (size_t)(bm + wr*64 + i*16 + hg*4 + rr);
      #pragma unroll
      for (int j = 0; j < 4; ++j) {
        int gc = bn + wc*64 + j*16 + lid;
        float v = acc[i][j][rr];
        if (ADDX) v += X[gr * ldx + gc];
        C[gr * ldc + coff + gc] = v;
      }
    }
  }
}

// ---------------- RoPE: Q in-place, K -> pre-split f16 buffers ----------------
__global__ __launch_bounds__(256) void rope_kernel(float* __restrict__ qkv,
    const float* __restrict__ fc, const float* __restrict__ fs,
    f16* __restrict__ Kh, f16* __restrict__ Kl) {
  int idx = blockIdx.x * 256 + threadIdx.x;
  constexpr int NQ = kB*kS*kH*(kHD/2);
  constexpr int NK = kB*kS*kKVH*(kHD/2);
  if (idx < NQ) {
    int i = idx & 63, h = (idx >> 6) & 15, s = (idx >> 10) & 1023, b = idx >> 20;
    size_t base = ((size_t)(b*kS + s))*kQKVN + h*kHD + 2*i;
    float c = fc[s*64 + i], sn = fs[s*64 + i];
    float xr = qkv[base], xi = qkv[base+1];
    qkv[base]   = xr*c - xi*sn;
    qkv[base+1] = xr*sn + xi*c;
  } else {
    int j = idx - NQ; if (j >= NK) return;
    int i = j & 63, h = (j >> 6) & 3, s = (j >> 8) & 1023, b = j >> 18;
    size_t src = ((size_t)(b*kS + s))*kQKVN + kH*kHD + h*kHD + 2*i;
    float c = fc[s*64 + i], sn = fs[s*64 + i];
    float xr = qkv[src], xi = qkv[src+1];
    float o0 = xr*c - xi*sn, o1 = xr*sn + xi*c;
    size_t dst = (((size_t)(b*kKVH + h))*kS + s)*kHD + 2*i;
    f16 h0 = (f16)o0, h1 = (f16)o1;
    Kh[dst]   = h0; Kl[dst]   = (f16)(o0 - (float)h0);
    Kh[dst+1] = h1; Kl[dst+1] = (f16)(o1 - (float)h1);
  }
}

// ---------------- split-f16 MFMA flash attention (pre-split K/V) ----------------
__global__ __launch_bounds__(256) void attn_sf16_kernel(const float* __restrict__ qkv,
    const f16* __restrict__ Ksh, const f16* __restrict__ Ksl,
    const f16* __restrict__ vTh, const f16* __restrict__ vTl,
    float* __restrict__ out) {
  int qt = (int)gridDim.x - 1 - blockIdx.x;
  int h = blockIdx.y, b = blockIdx.z;
  int kvh = h >> 2;
  int q0 = qt * 64;
  __shared__ __align__(16) char Kh[64*128*2], Kl[64*128*2];
  __shared__ __align__(16) char Vh[128*64*2], Vl[128*64*2];
  __shared__ __align__(16) char Ph[4][16*64*2], Pl[4][16*64*2];
  int tid = threadIdx.x, lane = tid & 63, w = tid >> 6;
  int hg = lane >> 4, lid = lane & 15;

  f16x8 qh[4], ql[4];
  {
    const float* qrow = qkv + (size_t)(b*kS + q0 + w*16 + lid) * kQKVN + h*kHD;
    #pragma unroll
    for (int ks = 0; ks < 4; ++ks) {
      float4 a = *(const float4*)(qrow + ks*32 + hg*8);
      float4 c = *(const float4*)(qrow + ks*32 + hg*8 + 4);
      split8v(a, c, qh[ks], ql[ks]);
    }
  }
  f32x4 oacc[8] = {};
  float m[4] = {-3.0e38f, -3.0e38f, -3.0e38f, -3.0e38f};
  float lsum[4] = {};
  char* Phw = Ph[w];
  char* Plw = Pl[w];

  for (int kt = 0; kt <= qt; ++kt) {
    __syncthreads();
    {
      int r = tid >> 2, c0 = (tid & 3) * 32;
      const f16* khr = Ksh + ((size_t)(b*kKVH + kvh)*kS + kt*64 + r) * kHD + c0;
      const f16* klr = Ksl + ((size_t)(b*kKVH + kvh)*kS + kt*64 + r) * kHD + c0;
      #pragma unroll
      for (int s8 = 0; s8 < 4; ++s8) {
        int4 hi = *(const int4*)(khr + s8*8);
        int4 lo = *(const int4*)(klr + s8*8);
        int off = (r*256 + c0*2 + s8*16) ^ ((r & 7) << 4);
        *(int4*)(Kh + off) = hi;
        *(int4*)(Kl + off) = lo;
      }
    }
    {
      int r = tid >> 1, c0 = (tid & 1) * 32;
      const f16* vhr = vTh + (size_t)(b*kKVH*kHD + kvh*kHD + r) * kS + kt*64 + c0;
      const f16* vlr = vTl + (size_t)(b*kKVH*kHD + kvh*kHD + r) * kS + kt*64 + c0;
      #pragma unroll
      for (int s8 = 0; s8 < 4; ++s8) {
        int4 hi = *(const int4*)(vhr + s8*8);
        int4 lo = *(const int4*)(vlr + s8*8);
        int off = (r*128 + c0*2 + s8*16) ^ ((r & 7) << 4);
        *(int4*)(Vh + off) = hi;
        *(int4*)(Vl + off) = lo;
      }
    }
    __syncthreads();

    f32x4 sacc[4] = {};
    #pragma unroll
    for (int ks = 0; ks < 4; ++ks) {
      #pragma unroll
      for (int j = 0; j < 4; ++j) {
        int rB = j*16 + lid;
        int off = (rB*256 + ks*64 + hg*16) ^ ((rB & 7) << 4);
        f16x8 kh = *(const f16x8*)(Kh + off);
        f16x8 klo = *(const f16x8*)(Kl + off);
        sacc[j] = __builtin_amdgcn_mfma_f32_16x16x32_f16(qh[ks], kh, sacc[j], 0, 0, 0);
        sacc[j] = __builtin_amdgcn_mfma_f32_16x16x32_f16(qh[ks], klo, sacc[j], 0, 0, 0);
        sacc[j] = __builtin_amdgcn_mfma_f32_16x16x32_f16(ql[ks], kh, sacc[j], 0, 0, 0);
      }
    }
    float s[4][4], ps[4][4];
    bool diag = (kt == qt);
    #pragma unroll
    for (int j = 0; j < 4; ++j)
      #pragma unroll
      for (int r = 0; r < 4; ++r) {
        float v = sacc[j][r] * kScale;
        if (diag) {
          int kvabs = kt*64 + j*16 + lid;
          int qabs = q0 + w*16 + hg*4 + r;
          if (kvabs > qabs) v = kNeg;
        }
        s[j][r] = v;
      }
    float pm[4], cf[4];
    #pragma unroll
    for (int r = 0; r < 4; ++r) {
      pm[r] = fmaxf(fmaxf(s[0][r], s[1][r]), fmaxf(s[2][r], s[3][r]));
      #pragma unroll
      for (int msk = 1; msk < 16; msk <<= 1) pm[r] = fmaxf(pm[r], __shfl_xor(pm[r], msk));
      float mn = fmaxf(m[r], pm[r]);
      cf[r] = __expf(m[r] - mn);
      m[r] = mn;
    }
    #pragma unroll
    for (int j2 = 0; j2 < 8; ++j2)
      #pragma unroll
      for (int r = 0; r < 4; ++r) oacc[j2][r] *= cf[r];
    float rs[4] = {};
    #pragma unroll
    for (int j = 0; j < 4; ++j)
      #pragma unroll
      for (int r = 0; r < 4; ++r) {
        float p = __expf(s[j][r] - m[r]);
        ps[j][r] = p;
        rs[r] += p;
      }
    #pragma unroll
    for (int r = 0; r < 4; ++r) lsum[r] = lsum[r]*cf[r] + rs[r];
    #pragma unroll
    for (int j = 0; j < 4; ++j)
      #pragma unroll
      for (int r = 0; r < 4; ++r) {
        int q = hg*4 + r;
        int off = (q*128 + (j*16 + lid)*2) ^ ((q & 7) << 4);
        f16 ph = (f16)ps[j][r];
        *(f16*)(Phw + off) = ph;
        *(f16*)(Plw + off) = (f16)(ps[j][r] - (float)ph);
      }
    #pragma unroll
    for (int kk2 = 0; kk2 < 2; ++kk2) {
      int oP = (lid*128 + kk2*64 + hg*16) ^ ((lid & 7) << 4);
      f16x8 pa_h = *(const f16x8*)(Phw + oP);
      f16x8 pa_l = *(const f16x8*)(Plw + oP);
      #pragma unroll
      for (int j2 = 0; j2 < 8; ++j2) {
        int rV = j2*16 + lid;
        int off = (rV*128 + kk2*64 + hg*16) ^ ((rV & 7) << 4);
        f16x8 vh = *(const f16x8*)(Vh + off);
        f16x8 vl = *(const f16x8*)(Vl + off);
        oacc[j2] = __builtin_amdgcn_mfma_f32_16x16x32_f16(pa_h, vh, oacc[j2], 0, 0, 0);
        oacc[j2] = __builtin_amdgcn_mfma_f32_16x16x32_f16(pa_h, vl, oacc[j2], 0, 0, 0);
        oacc[j2] = __builtin_amdgcn_mfma_f32_16x16x32_f16(pa_l, vh, oacc[j2], 0, 0, 0);
      }
    }
  }
  #pragma unroll
  for (int r = 0; r < 4; ++r) {
    #pragma unroll
    for (int msk = 1; msk < 16; msk <<= 1) lsum[r] += __shfl_xor(lsum[r], msk);
    lsum[r] = 1.f / lsum[r];
  }
  #pragma unroll
  for (int j2 = 0; j2 < 8; ++j2)
    #pragma unroll
    for (int r = 0; r < 4; ++r) {
      size_t o = (size_t)(b*kS + q0 + w*16 + hg*4 + r) * kD + h*kHD + j2*16 + lid;
      out[o] = oacc[j2][r] * lsum[r];
    }
}

// ---------------- gate / prefix+table ----------------
__global__ void zero_counts_kernel(int* counts) {
  if (threadIdx.x < kE) counts[threadIdx.x] = 0;
}

__global__ __launch_bounds__(64) void gate_kernel(const float* __restrict__ h1,
    const float* __restrict__ wn, const float* __restrict__ gw,
    int* __restrict__ packA, int* __restrict__ packB,
    float* __restrict__ cA, float* __restrict__ cB,
    int* __restrict__ lists, int* __restrict__ counts) {
  int row = blockIdx.x, lane = threadIdx.x;
  const float* x = h1 + (size_t)row * kD;
  float ss = 0.f;
  for (int d = lane; d < kD; d += 64) { float v = x[d]; ss = fmaf(v, v, ss); }
  #pragma unroll
  for (int off = 32; off; off >>= 1) ss += __shfl_xor(ss, off);
  float rs = rsqrtf(ss * (1.0f/kD) + kEps);
  float acc[kE] = {};
  for (int d = lane; d < kD; d += 64) {
    float g = x[d] * rs * wn[d];
    const float* gr = gw + (size_t)d * kE;
    #pragma unroll
    for (int e = 0; e < kE; ++e) acc[e] = fmaf(g, gr[e], acc[e]);
  }
  #pragma unroll
  for (int e = 0; e < kE; ++e)
    #pragma unroll
    for (int off = 32; off; off >>= 1) acc[e] += __shfl_xor(acc[e], off);
  if (lane == 0) {
    int i1 = 0; float l1 = acc[0];
    #pragma unroll
    for (int e = 1; e < kE; ++e) if (acc[e] > l1) { l1 = acc[e]; i1 = e; }
    int i2 = -1; float l2 = -3.4e38f;
    #pragma unroll
    for (int e = 0; e < kE; ++e) if (e != i1 && acc[e] > l2) { l2 = acc[e]; i2 = e; }
    float e2 = __expf(l2 - l1);
    float inv = 1.f / (1.f + e2);
    int p1 = atomicAdd(&counts[i1], 1); lists[i1*kRows + p1] = row;
    int p2 = atomicAdd(&counts[i2], 1); lists[i2*kRows + p2] = row;
    packA[row] = i1*2048 + p1; cA[row] = inv;
    packB[row] = i2*2048 + p2; cB[row] = e2 * inv;
  }
}

__global__ void prefix_kernel(const int* __restrict__ counts,
    int* __restrict__ padbase, int* __restrict__ tileTab) {
  if (threadIdx.x == 0) {
    int base = 0, idx = 0;
    for (int e = 0; e < kE; ++e) {
      padbase[e] = base;
      int nt = (counts[e] + 127) >> 7;
      for (int t = 0; t < nt; ++t) tileTab[idx++] = (e << 8) | t;
      base += nt << 7;
    }
    for (; idx < kMaxTiles; ++idx) tileTab[idx] = -1;
  }
}

// ------- MoE up-proj (paired w1|w3 cols, fused silu, 2-phase dbuf) -------
__global__ __launch_bounds__(256) void gemm_up_kernel(
    const u16* __restrict__ A, const u16* __restrict__ WUT,
    u16* __restrict__ hid, const int* __restrict__ lists,
    const int* __restrict__ counts, const int* __restrict__ padbase,
    const int* __restrict__ tileTab) {
  int tab = tileTab[blockIdx.y];
  if (tab < 0) return;
  int e = tab >> 8, mb = tab & 255;
  int cnt = counts[e];
  int bm = mb * 128;
  int slot0 = padbase[e] + bm;
  const int* ids = lists + e * kRows;
  int g = blockIdx.x;                               // n-group (64 cols of w1 + 64 of w3)
  const u16* Bt = WUT + (size_t)e * 8192 * kD + (size_t)g * 128 * kD;
  __shared__ __align__(16) u16 SM[32768];           // 64 KB
  u16* As = SM;                                     // [2][8192]
  u16* Bs = SM + 16384;                             // [2][8192]
  int tid = threadIdx.x, lane = tid & 63, w = tid >> 6;
  int wr = w >> 1, wc = w & 1;
  int hg = lane >> 4, lid = lane & 15;
  f32x4 acc[4][4] = {};
  const u16 *aP[4], *bP[4];
  #pragma unroll
  for (int j = 0; j < 4; ++j) {
    int r = w*32 + j*8 + (lane >> 3);
    int colc = ((lane & 7) ^ (r & 7)) * 8;
    int rr = bm + r; if (rr >= cnt) rr = cnt - 1;
    aP[j] = A + (size_t)ids[rr] * kD + colc;
    bP[j] = Bt + (size_t)r * kD + colc;
  }
  // prologue: stage kt=0 into buffer 0
  #pragma unroll
  for (int j = 0; j < 4; ++j) {
    int lb = w*2048 + j*512;
    gll16(aP[j], &As[lb]);
    gll16(bP[j], &Bs[lb]);
  }
  __syncthreads();
  for (int t = 0; t < 32; ++t) {
    int cur = t & 1;
    if (t + 1 < 32) {
      int kt = (t + 1) * 64;
      int nb = (cur ^ 1) * 8192;
      #pragma unroll
      for (int j = 0; j < 4; ++j) {
        int lb = nb + w*2048 + j*512;
        gll16(aP[j] + kt, &As[lb]);
        gll16(bP[j] + kt, &Bs[lb]);
      }
    }
    const char* AsB = (const char*)(As + cur*8192);
    const char* BsB = (const char*)(Bs + cur*8192);
    #pragma unroll
    for (int kk = 0; kk < 2; ++kk) {
      bf16x8 af[4], bfv[4];
      #pragma unroll
      for (int f = 0; f < 4; ++f) {
        int rA = wr*64 + f*16 + lid;
        af[f] = *(const bf16x8*)(AsB + ((rA*128 + kk*64 + hg*16) ^ ((rA & 7) << 4)));
        int rB = wc*64 + f*16 + lid;
        bfv[f] = *(const bf16x8*)(BsB + ((rB*128 + kk*64 + hg*16) ^ ((rB & 7) << 4)));
      }
      #pragma unroll
      for (int i = 0; i < 4; ++i)
        #pragma unroll
        for (int j = 0; j < 4; ++j)
          acc[i][j] = __builtin_amdgcn_mfma_f32_16x16x32_bf16(af[i], bfv[j], acc[i][j], 0, 0, 0);
    }
    __syncthreads();
  }
  // epilogue: exchange g1 (wc=0) -> silu(g1)*g3 (wc=1), write hid
  float* Xch = (float*)SM;                          // [128][64] f32 = 32KB
  if (wc == 0) {
    #pragma unroll
    for (int i = 0; i < 4; ++i)
      #pragma unroll
      for (int rr = 0; rr < 4; ++rr) {
        int row = wr*64 + i*16 + hg*4 + rr;
        #pragma unroll
        for (int j = 0; j < 4; ++j)
          Xch[row*64 + j*16 + lid] = acc[i][j][rr];
      }
  }
  __syncthreads();
  if (wc == 1) {
    #pragma unroll
    for (int i = 0; i < 4; ++i)
      #pragma unroll
      for (int rr = 0; rr < 4; ++rr) {
        int row = wr*64 + i*16 + hg*4 + rr;
        u16* orow = hid + (size_t)(slot0 + row) * kHID + g*64;
        #pragma unroll
        for (int j = 0; j < 4; ++j) {
          int col = j*16 + lid;
          float g1 = Xch[row*64 + col];
          float g3 = acc[i][j][rr];
          orow[col] = f2bf(g1 / (1.f + __expf(-g1)) * g3);
        }
      }
  }
}

// ------- MoE down-proj (2-phase dbuf) -------
__global__ __launch_bounds__(256) void gemm_down_kernel(
    const u16* __restrict__ hid, const u16* __restrict__ W2T,
    u16* __restrict__ ff, const int* __restrict__ padbase,
    const int* __restrict__ tileTab) {
  int tab = tileTab[blockIdx.y];
  if (tab < 0) return;
  int e = tab >> 8, mb = tab & 255;
  int slot0 = padbase[e] + mb * 128;
  const u16* Bt = W2T + (size_t)e * kD * kHID;
  int bn = blockIdx.x * 128;
  __shared__ __align__(16) u16 SM[32768];
  u16* As = SM;
  u16* Bs = SM + 16384;
  int tid = threadIdx.x, lane = tid & 63, w = tid >> 6;
  int wr = w >> 1, wc = w & 1;
  int hg = lane >> 4, lid = lane & 15;
  f32x4 acc[4][4] = {};
  const u16 *aP[4], *bP[4];
  #pragma unroll
  for (int j = 0; j < 4; ++j) {
    int r = w*32 + j*8 + (lane >> 3);
    int colc = ((lane & 7) ^ (r & 7)) * 8;
    aP[j] = hid + (size_t)(slot0 + r) * kHID + colc;
    bP[j] = Bt + (size_t)(bn + r) * kHID + colc;
  }
  #pragma unroll
  for (int j = 0; j < 4; ++j) {
    int lb = w*2048 + j*512;
    gll16(aP[j], &As[lb]);
    gll16(bP[j], &Bs[lb]);
  }
  __syncthreads();
  for (int t = 0; t < 64; ++t) {
    int cur = t & 1;
    if (t + 1 < 64) {
      int kt = (t + 1) * 64;
      int nb = (cur ^ 1) * 8192;
      #pragma unroll
      for (int j = 0; j < 4; ++j) {
        int lb = nb + w*2048 + j*512;
        gll16(aP[j] + kt, &As[lb]);
        gll16(bP[j] + kt, &Bs[lb]);
      }
    }
    const char* AsB = (const char*)(As + cur*8192);
    const char* BsB = (const char*)(Bs + cur*8192);
    #pragma unroll
    for (int kk = 0; kk < 2; ++kk) {
      bf16x8 af[4], bfv[4];
      #pragma unroll
      for (int f = 0; f < 4; ++f) {
        int rA = wr*64 + f*16 + lid;
        af[f] = *(const bf16x8*)(AsB + ((rA*128 + kk*64 + hg*16) ^ ((rA & 7) << 4)));
        int rB = wc*64 + f*16 + lid;
        bfv[f] = *(const bf16x8*)(BsB + ((rB*128 + kk*64 + hg*16) ^ ((rB & 7) << 4)));
      }
      #pragma unroll
      for (int i = 0; i < 4; ++i)
        #pragma unroll
        for (int j = 0; j < 4; ++j)
          acc[i][j] = __builtin_amdgcn_mfma_f32_16x16x32_bf16(af[i], bfv[j], acc[i][j], 0, 0, 0);
    }
    __syncthreads();
  }
  #pragma unroll
  for (int i = 0; i < 4; ++i)
    #pragma unroll
    for (int rr = 0; rr < 4; ++rr) {
      int row = wr*64 + i*16 + hg*4 + rr;
      u16* orow = ff + (size_t)(slot0 + row) * kD + bn;
      #pragma unroll
      for (int j = 0; j < 4; ++j)
        orow[wc*64 + j*16 + lid] = f2bf(acc[i][j][rr]);
    }
}

// ---------------- combine ----------------
__global__ __launch_bounds__(256) void moe_combine_kernel(
    const u16* __restrict__ ff, const int* __restrict__ padbase,
    const int* __restrict__ packA, const int* __restrict__ packB,
    const float* __restrict__ cA, const float* __restrict__ cB,
    float* __restrict__ outp) {
  int row = blockIdx.x, tid = threadIdx.x;
  int pa = packA[row], pb = packB[row];
  int sa = padbase[pa >> 11] + (pa & 2047);
  int sb = padbase[pb >> 11] + (pb & 2047);
  float ca = cA[row], cb = cB[row];
  union { int4 i4; u16 u[8]; } va, vb;
  va.i4 = *(const int4*)(ff + (size_t)sa * kD + tid*8);
  vb.i4 = *(const int4*)(ff + (size_t)sb * kD + tid*8);
  float* o = outp + (size_t)row * kD + tid*8;
  float4 o0 = *(const float4*)o;
  float4 o1 = *(const float4*)(o + 4);
  o0.x += ca*bf2f(va.u[0]) + cb*bf2f(vb.u[0]);
  o0.y += ca*bf2f(va.u[1]) + cb*bf2f(vb.u[1]);
  o0.z += ca*bf2f(va.u[2]) + cb*bf2f(vb.u[2]);
  o0.w += ca*bf2f(va.u[3]) + cb*bf2f(vb.u[3]);
  o1.x += ca*bf2f(va.u[4]) + cb*bf2f(vb.u[4]);
  o1.y += ca*bf2f(va.u[5]) + cb*bf2f(vb.u[5]);
  o1.z += ca*bf2f(va.u[6]) + cb*bf2f(vb.u[6]);
  o1.w += ca*bf2f(va.u[7]) + cb*bf2f(vb.u[7]);
  *(float4*)o = o0;
  *(float4*)(o + 4) = o1;
}

// ---------------- host launcher ----------------
extern "C" void kernel_launch(void* const* d_in, const int* in_sizes, int n_in,
                              void* d_out, int out_size, void* d_ws, size_t ws_size,
                              hipStream_t stream) {
  const float* x    = (const float*)d_in[0];
  const float* fcos = (const float*)d_in[1];
  const float* fsin = (const float*)d_in[2];
  const float* anw  = (const float*)d_in[5];
  const float* fnw  = (const float*)d_in[6];
  const float* wq   = (const float*)d_in[7];
  const float* wk   = (const float*)d_in[8];
  const float* wv   = (const float*)d_in[9];
  const float* wo   = (const float*)d_in[10];
  const float* gw   = (const float*)d_in[11];
  const float* w1   = (const float*)d_in[12];
  const float* w2   = (const float*)d_in[13];
  const float* w3   = (const float*)d_in[14];
  float* outp = (float*)d_out;

  char* ws = (char*)d_ws;
  size_t off = 0;
  auto alloc = [&](size_t bytes) -> void* {
    void* p = ws + off; off += (bytes + 255) & ~(size_t)255; return p;
  };
  f16* h16h   = (f16*)alloc((size_t)kRows*kD*2);
  f16* h16l   = (f16*)alloc((size_t)kRows*kD*2);
  float* qkv  = (float*)alloc((size_t)kRows*kQKVN*4);
  f16* Ksh    = (f16*)alloc((size_t)kB*kKVH*kS*kHD*2);
  f16* Ksl    = (f16*)alloc((size_t)kB*kKVH*kS*kHD*2);
  f16* vTh    = (f16*)alloc((size_t)kB*kKVH*kHD*kS*2);
  f16* vTl    = (f16*)alloc((size_t)kB*kKVH*kHD*kS*2);
  float* attno= (float*)alloc((size_t)kRows*kD*4);
  f16* a16h   = (f16*)alloc((size_t)kRows*kD*2);
  f16* a16l   = (f16*)alloc((size_t)kRows*kD*2);
  u16* tbf    = (u16*)alloc((size_t)kRows*kD*2);
  int* packA  = (int*)alloc(kRows*4);
  int* packB  = (int*)alloc(kRows*4);
  float* cAv  = (float*)alloc(kRows*4);
  float* cBv  = (float*)alloc(kRows*4);
  int* counts = (int*)alloc(kE*4);
  int* padbase= (int*)alloc(kE*4);
  int* tileTab= (int*)alloc(kMaxTiles*4);
  int* lists  = (int*)alloc((size_t)kE*kRows*4);
  f16* Bqh    = (f16*)alloc((size_t)kQKVN*kD*2);
  f16* Bql    = (f16*)alloc((size_t)kQKVN*kD*2);
  f16* Bwh    = (f16*)alloc((size_t)kD*kD*2);
  f16* Bwl    = (f16*)alloc((size_t)kD*kD*2);
  u16* hid    = (u16*)alloc((size_t)kSlotsPad*kHID*2);
  u16* ffb    = (u16*)alloc((size_t)kSlotsPad*kD*2);
  u16* wUT    = (u16*)alloc((size_t)kE*8192*kD*2);
  u16* w2T    = (u16*)alloc((size_t)kE*kD*kHID*2);

  // ---- weight prep ----
  transpose_split_kernel<<<dim3(kD/32, kD/32), dim3(32,8), 0, stream>>>(wq, Bqh, Bql, kD, 2048, 0, kD);
  transpose_split_kernel<<<dim3(512/32, kD/32), dim3(32,8), 0, stream>>>(wk, Bqh, Bql, kD, 512, 2048, kD);
  transpose_split_kernel<<<dim3(512/32, kD/32), dim3(32,8), 0, stream>>>(wv, Bqh, Bql, kD, 512, 2560, kD);
  transpose_split_kernel<<<dim3(kD/32, kD/32), dim3(32,8), 0, stream>>>(wo, Bwh, Bwl, kD, kD, 0, kD);
  transpose_up_kernel<<<dim3(kHID/64, kD/64, kE), 256, 0, stream>>>(w1, wUT, 0);
  transpose_up_kernel<<<dim3(kHID/64, kD/64, kE), 256, 0, stream>>>(w3, wUT, 1);
  transpose_w2_kernel<<<dim3(kD/64, kHID/64, kE), 256, 0, stream>>>(w2, w2T);

  // ---- attention path (split-f16 MFMA, f32-equivalent precision) ----
  rms_split_kernel<<<kRows, 256, 0, stream>>>(x, anw, h16h, h16l);
  gemm_sf16_kernel<false><<<dim3(kQKVN/128, kRows/128), 256, 0, stream>>>(
      h16h, h16l, kD, Bqh, Bql, qkv, kQKVN, 0, nullptr, 0, kD);
  rope_kernel<<<(kB*kS*(kH+kKVH)*(kHD/2))/256, 256, 0, stream>>>(qkv, fcos, fsin, Ksh, Ksl);
  vt_split_kernel<<<dim3(kS/32, (kKVH*kHD)/32, kB), dim3(32,8), 0, stream>>>(qkv, vTh, vTl);
  attn_sf16_kernel<<<dim3(kS/64, kH, kB), 256, 0, stream>>>(qkv, Ksh, Ksl, vTh, vTl, attno);
  split_kernel<<<(kRows*kD/8 + 255)/256, 256, 0, stream>>>(attno, a16h, a16l, kRows*kD/8);
  gemm_sf16_kernel<true><<<dim3(kD/128, kRows/128), 256, 0, stream>>>(
      a16h, a16l, kD, Bwh, Bwl, outp, kD, 0, x, kD, kD);

  // ---- gate ----
  zero_counts_kernel<<<1, 64, 0, stream>>>(counts);
  gate_kernel<<<kRows, 64, 0, stream>>>(outp, fnw, gw, packA, packB, cAv, cBv, lists, counts);
  prefix_kernel<<<1, 64, 0, stream>>>(counts, padbase, tileTab);
  rms_bf16_kernel<<<kRows, 256, 0, stream>>>(outp, fnw, tbf);

  // ---- MoE: 2 batched GEMMs + combine ----
  gemm_up_kernel<<<dim3(64, kMaxTiles), 256, 0, stream>>>(
      tbf, wUT, hid, lists, counts, padbase, tileTab);
  gemm_down_kernel<<<dim3(kD/128, kMaxTiles), 256, 0, stream>>>(
      hid, w2T, ffb, padbase, tileTab);
  moe_combine_kernel<<<kRows, 256, 0, stream>>>(
      ffb, padbase, packA, packB, cAv, cBv, outp);
}